// Round 1
// baseline (1847.041 us; speedup 1.0000x reference)
//
#include <hip/hip_runtime.h>
#include <hip/hip_bf16.h>
#include <stdint.h>

typedef unsigned short u16;

// B=32, T=64, N=2048, HID=256, HEADS=8, DH=32, BOT=64, MAX_LAG=7
// rows = B*N = 65536

__device__ __forceinline__ float bf2f(u16 u) {
  union { float f; uint32_t i; } x; x.i = ((uint32_t)u) << 16; return x.f;
}
__device__ __forceinline__ u16 f2bf(float f) {
  uint32_t u = __float_as_uint(f);
  u = (u + 0x7FFFu + ((u >> 16) & 1u)) >> 16;
  return (u16)u;
}

// ---------------- K0: prep (softmax(dw), folded delay weights) ----------------
__global__ void prep_k(const float* __restrict__ dlog, const float* __restrict__ w_dp,
                       const float* __restrict__ b_dp, const float* __restrict__ wql,
                       const float* __restrict__ bql,
                       float* __restrict__ dw, float* __restrict__ wl_d,
                       float* __restrict__ bl_p) {
  int t = threadIdx.x;
  if (t < 8) {
    float mx = dlog[0];
    for (int i = 1; i < 8; ++i) mx = fmaxf(mx, dlog[i]);
    float s = 0.f;
    for (int i = 0; i < 8; ++i) s += __expf(dlog[i] - mx);
    dw[t] = __expf(dlog[t] - mx) / s;
  }
  if (t < 192) {
    float s1 = 0.f, s2 = 0.f;
    for (int k = 0; k < 256; ++k) {
      float w = wql[k * 192 + t];
      s1 += w_dp[k] * w;
      s2 += b_dp[k] * w;
    }
    wl_d[t] = 0.1f * s1;
    bl_p[t] = bql[t] + 0.1f * s2;
  }
}

// ---------------- K1: delayed[b,n] = sum_tau dw[tau]*x[b,63-tau,n] ----------------
__global__ __launch_bounds__(256) void delayed_k(const float* __restrict__ x,
                                                 const float* __restrict__ dw,
                                                 float* __restrict__ delayed) {
  int r = blockIdx.x * 256 + threadIdx.x;   // 0..65535
  int b = r >> 11, n = r & 2047;
  const float* xb = x + (size_t)b * 64 * 2048;
  float acc = 0.f;
#pragma unroll
  for (int tau = 0; tau < 8; ++tau) acc += dw[tau] * xb[(size_t)(63 - tau) * 2048 + n];
  delayed[r] = acc;
}

// ---------------- generic tiled fp32 GEMM (BM=128,BN=128,BK=32; 8x8/thread) ----------------
struct GArgs {
  const float* features;
  const float* adj;
  const float* wql;
  const float* wqh; const float* bqh;
  const float* wol;
  const float* woh; const float* bol; const float* boh;
  const float* geow;
  const float* delayed; const float* wl_d; const float* bl_p;
  const float* kspart; const float* Mm;
  float* Vp; float* geo; float* attn;
  u16* low; u16* qf; u16* kf; u16* v; u16* outbf;
};

enum { MLOW = 0, MQKV, MVP, MATTN, MGEO, MFINAL };

template <int MODE>
__global__ __launch_bounds__(256) void gemm_k(GArgs ga) {
  constexpr int K  = (MODE == MLOW || MODE == MVP || MODE == MATTN) ? 256
                   : (MODE == MQKV ? 192 : (MODE == MGEO ? 2048 : 64));
  constexpr int NC = (MODE == MLOW) ? 192 : (MODE == MQKV ? 768 : (MODE == MFINAL ? 256 : 64));

  __shared__ float As[32][132];   // [k][m], padded (stride 132 -> bank skew 4)
  __shared__ float Bs[32][128];   // [k][n]
  __shared__ float ksB[32];
  __shared__ float dens[128];

  const int t = threadIdx.x;
  const int tx = t & 15, ty = t >> 4;
  const int ct = blockIdx.x, rt = blockIdx.y, bz = blockIdx.z;

  float acc[8][8];
#pragma unroll
  for (int i = 0; i < 8; ++i)
#pragma unroll
    for (int j = 0; j < 8; ++j) acc[i][j] = 0.f;

  float gb = 0.f;
  if constexpr (MODE == MFINAL) gb = 1.f / (1.f + __expf(-ga.geow[0]));

  const int bh = (MODE == MATTN) ? ((rt >> 4) * 8) : 0;  // b*8 for this row tile
  const float* Bptr =
      (MODE == MLOW)  ? ga.wql :
      (MODE == MQKV)  ? ga.wqh :
      (MODE == MVP)   ? ga.wol :
      (MODE == MATTN) ? ga.Mm + (size_t)(rt >> 4) * 256 * 64 :
      (MODE == MGEO)  ? (const float*)(ga.Vp + (size_t)bz * 2048 * 64) :
                        ga.woh;

  for (int k0 = 0; k0 < K; k0 += 32) {
    __syncthreads();
    // ---- stage A (128 rows x 32 k) ----
#pragma unroll
    for (int i = 0; i < 16; ++i) {
      int flat = t + i * 256;
      int mb = flat >> 5, kb = flat & 31;
      int row = rt * 128 + mb;
      int kg = k0 + kb;
      float av;
      if constexpr (MODE == MLOW)       av = ga.features[(size_t)row * 256 + kg];
      else if constexpr (MODE == MQKV)  av = bf2f(ga.low[(size_t)row * 192 + kg]);
      else if constexpr (MODE == MVP)   av = bf2f(ga.v[(size_t)row * 256 + kg]);
      else if constexpr (MODE == MATTN) av = bf2f(ga.qf[(size_t)row * 256 + kg]);
      else if constexpr (MODE == MGEO)  av = ga.adj[(size_t)row * 2048 + kg];
      else av = ga.attn[(size_t)row * 64 + kg] + gb * ga.geo[(size_t)row * 64 + kg] + ga.bol[kg];
      As[kb][mb] = av;
    }
    // ---- stage B (32 k x 128 n) ----
#pragma unroll
    for (int i = 0; i < 16; ++i) {
      int flat = t + i * 256;
      int kb = flat >> 7, nb = flat & 127;
      int ng = ct * 128 + nb;
      float bv = 0.f;
      if (ng < NC) bv = Bptr[(size_t)(k0 + kb) * NC + ng];
      Bs[kb][nb] = bv;
    }
    if constexpr (MODE == MATTN) {
      if (t < 32) {
        float s = 0.f;
#pragma unroll
        for (int c = 0; c < 8; ++c) s += ga.kspart[(size_t)(c * 256 + bh + (k0 >> 5)) * 32 + t];
        ksB[t] = s + 1e-8f;  // k_sum + 1e-8 (elementwise, per reference)
      }
    }
    __syncthreads();
    if constexpr (MODE == MATTN) {
      // per-(row, head=this chunk) denominator, then scale qf rows by 1/den in LDS
      if (t < 128) {
        float d = 0.f;
#pragma unroll
        for (int kk = 0; kk < 32; ++kk) d += As[kk][t] * ksB[kk];
        dens[t] = 1.f / (d + 1e-8f);
      }
      __syncthreads();
#pragma unroll
      for (int i = 0; i < 16; ++i) {
        int flat = t + i * 256;
        int mb = flat >> 5, kb = flat & 31;
        As[kb][mb] *= dens[mb];
      }
      __syncthreads();
    }
    // ---- compute ----
#pragma unroll
    for (int kk = 0; kk < 32; ++kk) {
      float4 a0 = *(const float4*)&As[kk][ty * 4];
      float4 a1 = *(const float4*)&As[kk][64 + ty * 4];
      float4 b0 = *(const float4*)&Bs[kk][tx * 4];
      float4 b1 = *(const float4*)&Bs[kk][64 + tx * 4];
      float av[8] = {a0.x, a0.y, a0.z, a0.w, a1.x, a1.y, a1.z, a1.w};
      float bv[8] = {b0.x, b0.y, b0.z, b0.w, b1.x, b1.y, b1.z, b1.w};
#pragma unroll
      for (int r = 0; r < 8; ++r)
#pragma unroll
        for (int c = 0; c < 8; ++c) acc[r][c] = fmaf(av[r], bv[c], acc[r][c]);
    }
  }

  // ---- epilogue ----
  // fragment mapping: rows {rt*128 + ty*4 + r , +64}, cols {ct*128 + tx*4 + c , +64}
#pragma unroll
  for (int r = 0; r < 8; ++r) {
    int row = rt * 128 + ((r < 4) ? (ty * 4 + r) : (64 + ty * 4 + (r - 4)));
#pragma unroll
    for (int g = 0; g < 2; ++g) {
      int col0 = ct * 128 + g * 64 + tx * 4;
      if (col0 >= NC) continue;
      float vv[4];
#pragma unroll
      for (int c = 0; c < 4; ++c) vv[c] = acc[r][g * 4 + c];

      if constexpr (MODE == MLOW) {
        float dl = ga.delayed[row];
        ushort4 q;
        q.x = f2bf(vv[0] + dl * ga.wl_d[col0 + 0] + ga.bl_p[col0 + 0]);
        q.y = f2bf(vv[1] + dl * ga.wl_d[col0 + 1] + ga.bl_p[col0 + 1]);
        q.z = f2bf(vv[2] + dl * ga.wl_d[col0 + 2] + ga.bl_p[col0 + 2]);
        q.w = f2bf(vv[3] + dl * ga.wl_d[col0 + 3] + ga.bl_p[col0 + 3]);
        *(ushort4*)(ga.low + (size_t)row * 192 + col0) = q;
      } else if constexpr (MODE == MQKV) {
        int third = col0 >> 8;
        int lc0 = col0 & 255;
        u16* dst = (third == 0) ? ga.qf : (third == 1 ? ga.kf : ga.v);
        ushort4 q;
        float w0 = vv[0] + ga.bqh[col0 + 0];
        float w1 = vv[1] + ga.bqh[col0 + 1];
        float w2 = vv[2] + ga.bqh[col0 + 2];
        float w3 = vv[3] + ga.bqh[col0 + 3];
        if (third < 2) {  // elu(x)+1 : x>0 ? x+1 : exp(x)
          w0 = (w0 > 0.f) ? (w0 + 1.f) : __expf(w0);
          w1 = (w1 > 0.f) ? (w1 + 1.f) : __expf(w1);
          w2 = (w2 > 0.f) ? (w2 + 1.f) : __expf(w2);
          w3 = (w3 > 0.f) ? (w3 + 1.f) : __expf(w3);
        }
        q.x = f2bf(w0); q.y = f2bf(w1); q.z = f2bf(w2); q.w = f2bf(w3);
        *(ushort4*)(dst + (size_t)row * 256 + lc0) = q;
      } else if constexpr (MODE == MVP || MODE == MATTN) {
        float* dst = (MODE == MVP) ? ga.Vp : ga.attn;
        float4 q = {vv[0], vv[1], vv[2], vv[3]};
        *(float4*)(dst + (size_t)row * 64 + col0) = q;
      } else if constexpr (MODE == MGEO) {
        float4 q = {vv[0], vv[1], vv[2], vv[3]};
        *(float4*)(ga.geo + ((size_t)bz * 2048 + row) * 64 + col0) = q;
      } else {  // MFINAL
        ushort4 q;
        q.x = f2bf(vv[0] + ga.boh[col0 + 0]);
        q.y = f2bf(vv[1] + ga.boh[col0 + 1]);
        q.z = f2bf(vv[2] + ga.boh[col0 + 2]);
        q.w = f2bf(vv[3] + ga.boh[col0 + 3]);
        *(ushort4*)(ga.outbf + (size_t)row * 256 + col0) = q;
      }
    }
  }
}

// ---------------- K4: kv & ksum partial reduction (deterministic, no atomics) ----------------
__global__ __launch_bounds__(64) void kvreduce_k(const u16* __restrict__ kf,
                                                 const u16* __restrict__ v,
                                                 float* __restrict__ kvpart,
                                                 float* __restrict__ kspart) {
  const int chunk = blockIdx.x, h = blockIdx.y, b = blockIdx.z;
  const int t = threadIdx.x;
  __shared__ float kfs[64][32], vs[64][32];
  const int d0 = (t >> 3) * 4, e0 = (t & 7) * 4;
  float acc[4][4];
#pragma unroll
  for (int i = 0; i < 4; ++i)
#pragma unroll
    for (int j = 0; j < 4; ++j) acc[i][j] = 0.f;
  float ks[4] = {0.f, 0.f, 0.f, 0.f};
  const int row0 = chunk * 256;
  for (int sub = 0; sub < 4; ++sub) {
    __syncthreads();
#pragma unroll
    for (int i = 0; i < 8; ++i) {
      int flat = t + i * 64;            // 0..511
      int rr = flat >> 3, c4 = (flat & 7) * 4;
      size_t g = ((size_t)(b * 2048 + row0 + sub * 64 + rr)) * 256 + h * 32 + c4;
      ushort4 ku = *(const ushort4*)(kf + g);
      ushort4 vu = *(const ushort4*)(v + g);
      kfs[rr][c4 + 0] = bf2f(ku.x); kfs[rr][c4 + 1] = bf2f(ku.y);
      kfs[rr][c4 + 2] = bf2f(ku.z); kfs[rr][c4 + 3] = bf2f(ku.w);
      vs[rr][c4 + 0] = bf2f(vu.x); vs[rr][c4 + 1] = bf2f(vu.y);
      vs[rr][c4 + 2] = bf2f(vu.z); vs[rr][c4 + 3] = bf2f(vu.w);
    }
    __syncthreads();
    for (int r = 0; r < 64; ++r) {
      float4 a = *(const float4*)&kfs[r][d0];
      float4 bb = *(const float4*)&vs[r][e0];
      float aa[4] = {a.x, a.y, a.z, a.w};
      float bbv[4] = {bb.x, bb.y, bb.z, bb.w};
#pragma unroll
      for (int i = 0; i < 4; ++i)
#pragma unroll
        for (int j = 0; j < 4; ++j) acc[i][j] = fmaf(aa[i], bbv[j], acc[i][j]);
      if (e0 == 0) {
        ks[0] += aa[0]; ks[1] += aa[1]; ks[2] += aa[2]; ks[3] += aa[3];
      }
    }
  }
  float* kvp = kvpart + (size_t)(chunk * 256 + b * 8 + h) * 1024;
#pragma unroll
  for (int i = 0; i < 4; ++i)
#pragma unroll
    for (int j = 0; j < 4; ++j) kvp[(d0 + i) * 32 + e0 + j] = acc[i][j];
  if (e0 == 0) {
    float* ksp = kspart + (size_t)(chunk * 256 + b * 8 + h) * 32;
#pragma unroll
    for (int i = 0; i < 4; ++i) ksp[d0 + i] = ks[i];
  }
}

// ---------------- K5: M[b,h] = (1-gb) * kv[b,h] @ Wl_h  (32x64 per (b,h)) ----------------
__global__ __launch_bounds__(64) void mmat_k(const float* __restrict__ kvpart,
                                             const float* __restrict__ wol,
                                             const float* __restrict__ geow,
                                             float* __restrict__ Mm) {
  const int bh = blockIdx.x;          // b*8+h
  const int h = bh & 7, b = bh >> 3;
  const int c = threadIdx.x;          // 0..63
  __shared__ float kvs[32][32];
  for (int i = c; i < 1024; i += 64) {
    float s = 0.f;
#pragma unroll
    for (int p = 0; p < 8; ++p) s += kvpart[(size_t)(p * 256 + bh) * 1024 + i];
    kvs[i >> 5][i & 31] = s;
  }
  __syncthreads();
  float one_m = 1.f - 1.f / (1.f + __expf(-geow[0]));
  float acc[32];
#pragma unroll
  for (int d = 0; d < 32; ++d) acc[d] = 0.f;
  for (int e = 0; e < 32; ++e) {
    float w = wol[(size_t)(h * 32 + e) * 64 + c];
#pragma unroll
    for (int d = 0; d < 32; ++d) acc[d] = fmaf(kvs[d][e], w, acc[d]);
  }
  float* mp = Mm + (size_t)b * 16384 + (size_t)h * 32 * 64 + c;
#pragma unroll
  for (int d = 0; d < 32; ++d) mp[d * 64] = one_m * acc[d];
}

// ---------------- K10: residual + LayerNorm ----------------
__global__ __launch_bounds__(256) void ln_k(const u16* __restrict__ outbf,
                                            const float* __restrict__ features,
                                            const float* __restrict__ gamma,
                                            const float* __restrict__ beta,
                                            float* __restrict__ y) {
  int wid = threadIdx.x >> 6, lane = threadIdx.x & 63;
  int row = blockIdx.x * 4 + wid;
  size_t base = (size_t)row * 256 + lane * 4;
  ushort4 ob = *(const ushort4*)(outbf + base);
  float4 ft = *(const float4*)(features + base);
  float y0 = bf2f(ob.x) + ft.x;
  float y1 = bf2f(ob.y) + ft.y;
  float y2 = bf2f(ob.z) + ft.z;
  float y3 = bf2f(ob.w) + ft.w;
  float s1 = y0 + y1 + y2 + y3;
  float s2 = y0 * y0 + y1 * y1 + y2 * y2 + y3 * y3;
#pragma unroll
  for (int off = 32; off; off >>= 1) {
    s1 += __shfl_xor(s1, off);
    s2 += __shfl_xor(s2, off);
  }
  float mu = s1 * (1.f / 256.f);
  float var = s2 * (1.f / 256.f) - mu * mu;
  float rstd = rsqrtf(fmaxf(var, 0.f) + 1e-5f);
  float4 g = *(const float4*)(gamma + lane * 4);
  float4 bt = *(const float4*)(beta + lane * 4);
  float4 o;
  o.x = (y0 - mu) * rstd * g.x + bt.x;
  o.y = (y1 - mu) * rstd * g.y + bt.y;
  o.z = (y2 - mu) * rstd * g.z + bt.z;
  o.w = (y3 - mu) * rstd * g.w + bt.w;
  *(float4*)(y + base) = o;
}

// ---------------- host ----------------
extern "C" void kernel_launch(void* const* d_in, const int* in_sizes, int n_in,
                              void* d_out, int out_size, void* d_ws, size_t ws_size,
                              hipStream_t stream) {
  const float* x     = (const float*)d_in[0];
  const float* feats = (const float*)d_in[1];
  const float* dlog  = (const float*)d_in[2];
  const float* w_dp  = (const float*)d_in[3];
  const float* b_dp  = (const float*)d_in[4];
  const float* wql   = (const float*)d_in[5];
  const float* bql   = (const float*)d_in[6];
  const float* wqh   = (const float*)d_in[7];
  const float* bqh   = (const float*)d_in[8];
  const float* wol   = (const float*)d_in[9];
  const float* bol   = (const float*)d_in[10];
  const float* woh   = (const float*)d_in[11];
  const float* boh   = (const float*)d_in[12];
  const float* adj   = (const float*)d_in[13];
  const float* geow  = (const float*)d_in[14];
  const float* gamma = (const float*)d_in[15];
  const float* beta  = (const float*)d_in[16];

  char* ws = (char*)d_ws;
  // layout (bytes); aliases exploit liveness; peak need ~136.9 MB
  constexpr size_t OFF_DW   = 0;                               // 32 B
  constexpr size_t OFF_WLD  = 1024;                            // 768 B
  constexpr size_t OFF_BLP  = 2048;                            // 768 B
  constexpr size_t OFF_DEL  = 4096;                            // 256 KB
  constexpr size_t OFF_LOW  = 266240;                          // bf16 65536x192 = 24 MB
  constexpr size_t OFF_QF   = 25432064;                        // bf16 65536x256 = 32 MB
  constexpr size_t OFF_KF   = 58986496;                        // bf16 32 MB
  constexpr size_t OFF_V    = 92540928;                        // bf16 32 MB
  constexpr size_t OFF_KVP  = 126095360;                       // 8x256x1024 f32 = 8 MB
  constexpr size_t OFF_KSP  = 134483968;                       // 8x256x32 f32 = 256 KB
  constexpr size_t OFF_MM   = 134746112;                       // 32x256x64 f32 = 2 MB
  constexpr size_t OFF_VP   = OFF_KF;                          // alias (kf dead after kvreduce)
  constexpr size_t OFF_GEO  = OFF_KF + 16777216;               // alias (kf upper half)
  constexpr size_t OFF_ATTN = OFF_LOW;                         // alias (low dead after qkv GEMM)
  constexpr size_t OFF_OUT  = OFF_QF;                          // alias (qf dead after attn GEMM)

  float* dw      = (float*)(ws + OFF_DW);
  float* wl_d    = (float*)(ws + OFF_WLD);
  float* bl_p    = (float*)(ws + OFF_BLP);
  float* delayed = (float*)(ws + OFF_DEL);
  float* kvpart  = (float*)(ws + OFF_KVP);
  float* kspart  = (float*)(ws + OFF_KSP);
  float* Mm      = (float*)(ws + OFF_MM);

  GArgs ga;
  ga.features = feats; ga.adj = adj;
  ga.wql = wql; ga.wqh = wqh; ga.bqh = bqh;
  ga.wol = wol; ga.woh = woh; ga.bol = bol; ga.boh = boh;
  ga.geow = geow;
  ga.delayed = delayed; ga.wl_d = wl_d; ga.bl_p = bl_p;
  ga.kspart = kspart; ga.Mm = Mm;
  ga.Vp   = (float*)(ws + OFF_VP);
  ga.geo  = (float*)(ws + OFF_GEO);
  ga.attn = (float*)(ws + OFF_ATTN);
  ga.low  = (u16*)(ws + OFF_LOW);
  ga.qf   = (u16*)(ws + OFF_QF);
  ga.kf   = (u16*)(ws + OFF_KF);
  ga.v    = (u16*)(ws + OFF_V);
  ga.outbf = (u16*)(ws + OFF_OUT);

  prep_k<<<1, 256, 0, stream>>>(dlog, w_dp, b_dp, wql, bql, dw, wl_d, bl_p);
  delayed_k<<<256, 256, 0, stream>>>(x, dw, delayed);
  gemm_k<MLOW><<<dim3(2, 512, 1), 256, 0, stream>>>(ga);     // low = features@Wql (+delay fold) -> bf16
  gemm_k<MQKV><<<dim3(6, 512, 1), 256, 0, stream>>>(ga);     // qkv = low@Wqh ; elu+1 -> qf,kf,v bf16
  kvreduce_k<<<dim3(8, 8, 32), 64, 0, stream>>>(ga.kf, ga.v, kvpart, kspart);
  mmat_k<<<256, 64, 0, stream>>>(kvpart, wol, geow, Mm);     // M = (1-gb)*kv_h@Wl_h
  gemm_k<MVP><<<dim3(1, 512, 1), 256, 0, stream>>>(ga);      // Vp = v@Wl
  gemm_k<MATTN><<<dim3(1, 512, 1), 256, 0, stream>>>(ga);    // attn_low = (qf/den)@blockdiag(M)
  gemm_k<MGEO><<<dim3(1, 16, 32), 256, 0, stream>>>(ga);     // geo_low = adj@Vp (per batch)
  gemm_k<MFINAL><<<dim3(2, 512, 1), 256, 0, stream>>>(ga);   // out = (attn+gb*geo+bol)@Woh + boh
  ln_k<<<16384, 256, 0, stream>>>(ga.outbf, feats, gamma, beta, (float*)d_out);
  (void)in_sizes; (void)n_in; (void)out_size; (void)ws_size;
}

// Round 2
// 563.795 us; speedup vs baseline: 3.2761x; 3.2761x over previous
//
#include <hip/hip_runtime.h>
#include <hip/hip_bf16.h>
#include <stdint.h>

typedef unsigned short u16;
typedef float f4v __attribute__((ext_vector_type(4)));
typedef short s8v __attribute__((ext_vector_type(8)));

// B=32, T=64, N=2048, HID=256, HEADS=8, DH=32, BOT=64, MAX_LAG=7 ; rows = 65536

__device__ __forceinline__ float bf2f(u16 u) {
  union { float f; uint32_t i; } x; x.i = ((uint32_t)u) << 16; return x.f;
}
__device__ __forceinline__ u16 f2bf(float f) {
  uint32_t u = __float_as_uint(f);
  u = (u + 0x7FFFu + ((u >> 16) & 1u)) >> 16;
  return (u16)u;
}
__device__ __forceinline__ void gload16(const void* g, void* l) {
  __builtin_amdgcn_global_load_lds((const __attribute__((address_space(1))) void*)g,
                                   (__attribute__((address_space(3))) void*)l, 16, 0, 0);
}

// ---------------- K0: prep (softmax(dw), folded delay weights) ----------------
__global__ void prep_k(const float* __restrict__ dlog, const float* __restrict__ w_dp,
                       const float* __restrict__ b_dp, const float* __restrict__ wql,
                       const float* __restrict__ bql,
                       float* __restrict__ dw, float* __restrict__ wl_d,
                       float* __restrict__ bl_p) {
  int t = threadIdx.x;
  if (t < 8) {
    float mx = dlog[0];
    for (int i = 1; i < 8; ++i) mx = fmaxf(mx, dlog[i]);
    float s = 0.f;
    for (int i = 0; i < 8; ++i) s += __expf(dlog[i] - mx);
    dw[t] = __expf(dlog[t] - mx) / s;
  }
  if (t < 192) {
    float s1 = 0.f, s2 = 0.f;
    for (int k = 0; k < 256; ++k) {
      float w = wql[k * 192 + t];
      s1 += w_dp[k] * w;
      s2 += b_dp[k] * w;
    }
    wl_d[t] = 0.1f * s1;
    bl_p[t] = bql[t] + 0.1f * s2;
  }
}

// ---------------- K1: delayed[b,n] ----------------
__global__ __launch_bounds__(256) void delayed_k(const float* __restrict__ x,
                                                 const float* __restrict__ dw,
                                                 float* __restrict__ delayed) {
  int r = blockIdx.x * 256 + threadIdx.x;
  int b = r >> 11, n = r & 2047;
  const float* xb = x + (size_t)b * 64 * 2048;
  float acc = 0.f;
#pragma unroll
  for (int tau = 0; tau < 8; ++tau) acc += dw[tau] * xb[(size_t)(63 - tau) * 2048 + n];
  delayed[r] = acc;
}

// ---------------- converts / transposes ----------------
__global__ __launch_bounds__(256) void cvt_k(const float* __restrict__ in, u16* __restrict__ out) {
  size_t i = ((size_t)blockIdx.x * 256 + threadIdx.x) * 4;
  float4 v = *(const float4*)(in + i);
  ushort4 q = {f2bf(v.x), f2bf(v.y), f2bf(v.z), f2bf(v.w)};
  *(ushort4*)(out + i) = q;
}

// out[n][k] = bf16(in[k][n]) for n<N else 0 ; out has K cols, grid = padN blocks
__global__ void tpose_k(const float* __restrict__ in, u16* __restrict__ out, int K, int N) {
  int n = blockIdx.x;
  for (int k = threadIdx.x; k < K; k += 64)
    out[(size_t)n * K + k] = f2bf(n < N ? in[(size_t)k * N + n] : 0.f);
}

// Vp f32 [(b,n)][64] -> Vp2T bf16 [(b*64+d)][2048 n]
__global__ __launch_bounds__(256) void vpt_k(const float* __restrict__ Vp, u16* __restrict__ vpt) {
  const int b = blockIdx.x >> 3, nt = blockIdx.x & 7;
  const int n0 = nt * 256;
  const int t = threadIdx.x;
  __shared__ u16 tile[64][260];
#pragma unroll
  for (int s = 0; s < 16; ++s) {
    int idx = t + s * 256;
    int nl = idx >> 4, dc = idx & 15;
    float4 v4 = *(const float4*)(Vp + (size_t)(b * 2048 + n0 + nl) * 64 + dc * 4);
    tile[dc * 4 + 0][nl] = f2bf(v4.x);
    tile[dc * 4 + 1][nl] = f2bf(v4.y);
    tile[dc * 4 + 2][nl] = f2bf(v4.z);
    tile[dc * 4 + 3][nl] = f2bf(v4.w);
  }
  __syncthreads();
#pragma unroll
  for (int s = 0; s < 16; ++s) {
    int idx = t + s * 256;
    int d = idx >> 6, nc = idx & 63;
    ushort4 q = {tile[d][nc * 4 + 0], tile[d][nc * 4 + 1],
                 tile[d][nc * 4 + 2], tile[d][nc * 4 + 3]};
    *(ushort4*)(vpt + (size_t)(b * 64 + d) * 2048 + n0 + nc * 4) = q;
  }
}

// ---------------- bf16 MFMA GEMM template (128x128 tile, BK=32, 4 waves) ----------------
struct MArgs {
  const u16* A;        // bf16 row-major [M][LDA]
  const float* Af32;   // GGEO: adj fp32 [2048][2048]
  const u16* Bt;       // bf16 row-major [Ncols][LDB]  (= B^T)
  const float* delayed; const float* wl_d; const float* bl_p;   // GLOW epilogue
  const float* bqh;                                             // GQKV epilogue
  u16* low; u16* qf; u16* kf; u16* v; u16* geo2b;
};

enum { GLOW = 0, GQKV = 1, GGEO = 2 };

template <int MODE>
__global__ __launch_bounds__(256) void mgemm_k(MArgs ma) {
  constexpr int K   = (MODE == GLOW) ? 256 : (MODE == GQKV) ? 192 : 2048;
  constexpr int NC  = (MODE == GLOW) ? 192 : (MODE == GQKV) ? 768 : 2048;
  constexpr int LDA = (MODE == GLOW) ? 256 : (MODE == GQKV) ? 192 : 2048;
  constexpr int LDB = (MODE == GLOW) ? 256 : (MODE == GQKV) ? 192 : 2048;

  __shared__ __align__(16) u16 Al[128 * 32];
  __shared__ __align__(16) u16 Bl[128 * 32];

  const int t = threadIdx.x;
  const int l = t & 63, w = t >> 6;
  const int wm = w >> 1, wn = w & 1;
  const int ct = blockIdx.x, rt = blockIdx.y;

  f4v acc[4][4] = {};

  for (int k0 = 0; k0 < K; k0 += 32) {
    __syncthreads();
#pragma unroll
    for (int s = 0; s < 2; ++s) {
      int c = s * 256 + t;
      int r = c >> 2, cc = c & 3;
      int g = cc ^ ((r >> 1) & 3);     // XOR chunk swizzle (involution)
      // ---- A tile [128][32] ----
      if constexpr (MODE == GGEO) {
        const float* src = ma.Af32 + (size_t)(rt * 128 + r) * LDA + k0 + g * 8;
        float4 x0 = *(const float4*)src;
        float4 x1 = *(const float4*)(src + 4);
        uint32_t q0 = (uint32_t)f2bf(x0.x) | ((uint32_t)f2bf(x0.y) << 16);
        uint32_t q1 = (uint32_t)f2bf(x0.z) | ((uint32_t)f2bf(x0.w) << 16);
        uint32_t q2 = (uint32_t)f2bf(x1.x) | ((uint32_t)f2bf(x1.y) << 16);
        uint32_t q3 = (uint32_t)f2bf(x1.z) | ((uint32_t)f2bf(x1.w) << 16);
        uint4 qq = {q0, q1, q2, q3};
        *(uint4*)&Al[c * 8] = qq;
      } else {
        gload16(ma.A + (size_t)(rt * 128 + r) * LDA + k0 + g * 8,
                (char*)Al + (s * 4 + w) * 1024);
      }
      // ---- Bt tile [128][32] ----
      gload16(ma.Bt + (size_t)(ct * 128 + r) * LDB + k0 + g * 8,
              (char*)Bl + (s * 4 + w) * 1024);
    }
    __syncthreads();

    s8v fa[4], fb[4];
#pragma unroll
    for (int mr = 0; mr < 4; ++mr) {
      int ra = wm * 64 + mr * 16 + (l & 15);
      int ca = (l >> 4) ^ ((ra >> 1) & 3);
      fa[mr] = *(const s8v*)(Al + ra * 32 + ca * 8);
    }
#pragma unroll
    for (int nr = 0; nr < 4; ++nr) {
      int rb = wn * 64 + nr * 16 + (l & 15);
      int cb = (l >> 4) ^ ((rb >> 1) & 3);
      fb[nr] = *(const s8v*)(Bl + rb * 32 + cb * 8);
    }
#pragma unroll
    for (int mr = 0; mr < 4; ++mr)
#pragma unroll
      for (int nr = 0; nr < 4; ++nr)
        acc[mr][nr] = __builtin_amdgcn_mfma_f32_16x16x32_bf16(fa[mr], fb[nr], acc[mr][nr], 0, 0, 0);
  }

  // ---- epilogue ----  D: col = lane&15, row = (lane>>4)*4 + reg   [m89-verified]
  const int r0 = rt * 128 + wm * 64, c0 = ct * 128 + wn * 64;
  const int lr = (l >> 4) * 4, lc = l & 15;
#pragma unroll
  for (int mr = 0; mr < 4; ++mr)
#pragma unroll
    for (int nr = 0; nr < 4; ++nr) {
      int col = c0 + nr * 16 + lc;
      if constexpr (MODE == GLOW) {
        if (col < 192) {
          float wd = ma.wl_d[col], bp = ma.bl_p[col];
#pragma unroll
          for (int i = 0; i < 4; ++i) {
            int row = r0 + mr * 16 + lr + i;
            float val = acc[mr][nr][i] + ma.delayed[row] * wd + bp;
            ma.low[(size_t)row * 192 + col] = f2bf(val);
          }
        }
      } else if constexpr (MODE == GQKV) {
        int third = col >> 8, lc2 = col & 255;
        float bias = ma.bqh[col];
        u16* dst = (third == 0) ? ma.qf : (third == 1 ? ma.kf : ma.v);
#pragma unroll
        for (int i = 0; i < 4; ++i) {
          int row = r0 + mr * 16 + lr + i;
          float val = acc[mr][nr][i] + bias;
          if (third < 2) val = (val > 0.f) ? (val + 1.f) : __expf(val);
          dst[(size_t)row * 256 + lc2] = f2bf(val);
        }
      } else {
#pragma unroll
        for (int i = 0; i < 4; ++i) {
          int row = r0 + mr * 16 + lr + i;
          ma.geo2b[(size_t)row * 2048 + col] = f2bf(acc[mr][nr][i]);
        }
      }
    }
}

// ---------------- fp32 tiled GEMM (remaining small GEMMs) ----------------
struct GArgs {
  const float* wol;
  const float* woh; const float* bol; const float* boh;
  const float* geow;
  const float* kspart; const float* Mm;
  float* Vp; float* attn;
  const u16* qf; const u16* v; const u16* geo2b;
  u16* outbf;
};

enum { MVP = 0, MATTN = 1, MFINAL = 2 };

template <int MODE>
__global__ __launch_bounds__(256) void gemm_k(GArgs ga) {
  constexpr int K  = (MODE == MFINAL) ? 64 : 256;
  constexpr int NC = (MODE == MFINAL) ? 256 : 64;

  __shared__ float As[32][132];
  __shared__ float Bs[32][128];
  __shared__ float ksB[32];
  __shared__ float dens[128];

  const int t = threadIdx.x;
  const int tx = t & 15, ty = t >> 4;
  const int ct = blockIdx.x, rt = blockIdx.y;

  float acc[8][8];
#pragma unroll
  for (int i = 0; i < 8; ++i)
#pragma unroll
    for (int j = 0; j < 8; ++j) acc[i][j] = 0.f;

  float gb = 0.f;
  if constexpr (MODE == MFINAL) gb = 1.f / (1.f + __expf(-ga.geow[0]));

  const int bh = (MODE == MATTN) ? ((rt >> 4) * 8) : 0;
  const float* Bptr =
      (MODE == MVP)   ? ga.wol :
      (MODE == MATTN) ? ga.Mm + (size_t)(rt >> 4) * 256 * 64 :
                        ga.woh;

  for (int k0 = 0; k0 < K; k0 += 32) {
    __syncthreads();
#pragma unroll
    for (int i = 0; i < 16; ++i) {
      int flat = t + i * 256;
      int mb = flat >> 5, kb = flat & 31;
      int row = rt * 128 + mb;
      int kg = k0 + kb;
      float av;
      if constexpr (MODE == MVP)        av = bf2f(ga.v[(size_t)row * 256 + kg]);
      else if constexpr (MODE == MATTN) av = bf2f(ga.qf[(size_t)row * 256 + kg]);
      else av = ga.attn[(size_t)row * 64 + kg]
              + gb * bf2f(ga.geo2b[(size_t)(row & 2047) * 2048 + (row >> 11) * 64 + kg])
              + ga.bol[kg];
      As[kb][mb] = av;
    }
#pragma unroll
    for (int i = 0; i < 16; ++i) {
      int flat = t + i * 256;
      int kb = flat >> 7, nb = flat & 127;
      int ng = ct * 128 + nb;
      float bv = 0.f;
      if (ng < NC) bv = Bptr[(size_t)(k0 + kb) * NC + ng];
      Bs[kb][nb] = bv;
    }
    if constexpr (MODE == MATTN) {
      if (t < 32) {
        float s = 0.f;
#pragma unroll
        for (int c = 0; c < 8; ++c) s += ga.kspart[(size_t)(c * 256 + bh + (k0 >> 5)) * 32 + t];
        ksB[t] = s + 1e-8f;
      }
    }
    __syncthreads();
    if constexpr (MODE == MATTN) {
      if (t < 128) {
        float d = 0.f;
#pragma unroll
        for (int kk = 0; kk < 32; ++kk) d += As[kk][t] * ksB[kk];
        dens[t] = 1.f / (d + 1e-8f);
      }
      __syncthreads();
#pragma unroll
      for (int i = 0; i < 16; ++i) {
        int flat = t + i * 256;
        int mb = flat >> 5, kb = flat & 31;
        As[kb][mb] *= dens[mb];
      }
      __syncthreads();
    }
#pragma unroll
    for (int kk = 0; kk < 32; ++kk) {
      float4 a0 = *(const float4*)&As[kk][ty * 4];
      float4 a1 = *(const float4*)&As[kk][64 + ty * 4];
      float4 b0 = *(const float4*)&Bs[kk][tx * 4];
      float4 b1 = *(const float4*)&Bs[kk][64 + tx * 4];
      float av[8] = {a0.x, a0.y, a0.z, a0.w, a1.x, a1.y, a1.z, a1.w};
      float bv[8] = {b0.x, b0.y, b0.z, b0.w, b1.x, b1.y, b1.z, b1.w};
#pragma unroll
      for (int r = 0; r < 8; ++r)
#pragma unroll
        for (int c = 0; c < 8; ++c) acc[r][c] = fmaf(av[r], bv[c], acc[r][c]);
    }
  }

#pragma unroll
  for (int r = 0; r < 8; ++r) {
    int row = rt * 128 + ((r < 4) ? (ty * 4 + r) : (64 + ty * 4 + (r - 4)));
#pragma unroll
    for (int g = 0; g < 2; ++g) {
      int col0 = ct * 128 + g * 64 + tx * 4;
      if (col0 >= NC) continue;
      float vv[4];
#pragma unroll
      for (int c = 0; c < 4; ++c) vv[c] = acc[r][g * 4 + c];

      if constexpr (MODE == MVP) {
        float4 q = {vv[0], vv[1], vv[2], vv[3]};
        *(float4*)(ga.Vp + (size_t)row * 64 + col0) = q;
      } else if constexpr (MODE == MATTN) {
        float4 q = {vv[0], vv[1], vv[2], vv[3]};
        *(float4*)(ga.attn + (size_t)row * 64 + col0) = q;
      } else {
        ushort4 q;
        q.x = f2bf(vv[0] + ga.boh[col0 + 0]);
        q.y = f2bf(vv[1] + ga.boh[col0 + 1]);
        q.z = f2bf(vv[2] + ga.boh[col0 + 2]);
        q.w = f2bf(vv[3] + ga.boh[col0 + 3]);
        *(ushort4*)(ga.outbf + (size_t)row * 256 + col0) = q;
      }
    }
  }
}

// ---------------- K4: kv & ksum partial reduction ----------------
__global__ __launch_bounds__(64) void kvreduce_k(const u16* __restrict__ kf,
                                                 const u16* __restrict__ v,
                                                 float* __restrict__ kvpart,
                                                 float* __restrict__ kspart) {
  const int chunk = blockIdx.x, h = blockIdx.y, b = blockIdx.z;
  const int t = threadIdx.x;
  __shared__ float kfs[64][32], vs[64][32];
  const int d0 = (t >> 3) * 4, e0 = (t & 7) * 4;
  float acc[4][4];
#pragma unroll
  for (int i = 0; i < 4; ++i)
#pragma unroll
    for (int j = 0; j < 4; ++j) acc[i][j] = 0.f;
  float ks[4] = {0.f, 0.f, 0.f, 0.f};
  const int row0 = chunk * 256;
  for (int sub = 0; sub < 4; ++sub) {
    __syncthreads();
#pragma unroll
    for (int i = 0; i < 8; ++i) {
      int flat = t + i * 64;
      int rr = flat >> 3, c4 = (flat & 7) * 4;
      size_t g = ((size_t)(b * 2048 + row0 + sub * 64 + rr)) * 256 + h * 32 + c4;
      ushort4 ku = *(const ushort4*)(kf + g);
      ushort4 vu = *(const ushort4*)(v + g);
      kfs[rr][c4 + 0] = bf2f(ku.x); kfs[rr][c4 + 1] = bf2f(ku.y);
      kfs[rr][c4 + 2] = bf2f(ku.z); kfs[rr][c4 + 3] = bf2f(ku.w);
      vs[rr][c4 + 0] = bf2f(vu.x); vs[rr][c4 + 1] = bf2f(vu.y);
      vs[rr][c4 + 2] = bf2f(vu.z); vs[rr][c4 + 3] = bf2f(vu.w);
    }
    __syncthreads();
    for (int r = 0; r < 64; ++r) {
      float4 a = *(const float4*)&kfs[r][d0];
      float4 bb = *(const float4*)&vs[r][e0];
      float aa[4] = {a.x, a.y, a.z, a.w};
      float bbv[4] = {bb.x, bb.y, bb.z, bb.w};
#pragma unroll
      for (int i = 0; i < 4; ++i)
#pragma unroll
        for (int j = 0; j < 4; ++j) acc[i][j] = fmaf(aa[i], bbv[j], acc[i][j]);
      if (e0 == 0) {
        ks[0] += aa[0]; ks[1] += aa[1]; ks[2] += aa[2]; ks[3] += aa[3];
      }
    }
  }
  float* kvp = kvpart + (size_t)(chunk * 256 + b * 8 + h) * 1024;
#pragma unroll
  for (int i = 0; i < 4; ++i)
#pragma unroll
    for (int j = 0; j < 4; ++j) kvp[(d0 + i) * 32 + e0 + j] = acc[i][j];
  if (e0 == 0) {
    float* ksp = kspart + (size_t)(chunk * 256 + b * 8 + h) * 32;
#pragma unroll
    for (int i = 0; i < 4; ++i) ksp[d0 + i] = ks[i];
  }
}

// ---------------- K5: M[b,h] = (1-gb) * kv[b,h] @ Wl_h ----------------
__global__ __launch_bounds__(64) void mmat_k(const float* __restrict__ kvpart,
                                             const float* __restrict__ wol,
                                             const float* __restrict__ geow,
                                             float* __restrict__ Mm) {
  const int bh = blockIdx.x;
  const int h = bh & 7, b = bh >> 3;
  const int c = threadIdx.x;
  __shared__ float kvs[32][32];
  for (int i = c; i < 1024; i += 64) {
    float s = 0.f;
#pragma unroll
    for (int p = 0; p < 8; ++p) s += kvpart[(size_t)(p * 256 + bh) * 1024 + i];
    kvs[i >> 5][i & 31] = s;
  }
  __syncthreads();
  float one_m = 1.f - 1.f / (1.f + __expf(-geow[0]));
  float acc[32];
#pragma unroll
  for (int d = 0; d < 32; ++d) acc[d] = 0.f;
  for (int e = 0; e < 32; ++e) {
    float w = wol[(size_t)(h * 32 + e) * 64 + c];
#pragma unroll
    for (int d = 0; d < 32; ++d) acc[d] = fmaf(kvs[d][e], w, acc[d]);
  }
  float* mp = Mm + (size_t)b * 16384 + (size_t)h * 32 * 64 + c;
#pragma unroll
  for (int d = 0; d < 32; ++d) mp[d * 64] = one_m * acc[d];
}

// ---------------- K10: residual + LayerNorm ----------------
__global__ __launch_bounds__(256) void ln_k(const u16* __restrict__ outbf,
                                            const float* __restrict__ features,
                                            const float* __restrict__ gamma,
                                            const float* __restrict__ beta,
                                            float* __restrict__ y) {
  int wid = threadIdx.x >> 6, lane = threadIdx.x & 63;
  int row = blockIdx.x * 4 + wid;
  size_t base = (size_t)row * 256 + lane * 4;
  ushort4 ob = *(const ushort4*)(outbf + base);
  float4 ft = *(const float4*)(features + base);
  float y0 = bf2f(ob.x) + ft.x;
  float y1 = bf2f(ob.y) + ft.y;
  float y2 = bf2f(ob.z) + ft.z;
  float y3 = bf2f(ob.w) + ft.w;
  float s1 = y0 + y1 + y2 + y3;
  float s2 = y0 * y0 + y1 * y1 + y2 * y2 + y3 * y3;
#pragma unroll
  for (int off = 32; off; off >>= 1) {
    s1 += __shfl_xor(s1, off);
    s2 += __shfl_xor(s2, off);
  }
  float mu = s1 * (1.f / 256.f);
  float var = s2 * (1.f / 256.f) - mu * mu;
  float rstd = rsqrtf(fmaxf(var, 0.f) + 1e-5f);
  float4 g = *(const float4*)(gamma + lane * 4);
  float4 bt = *(const float4*)(beta + lane * 4);
  float4 o;
  o.x = (y0 - mu) * rstd * g.x + bt.x;
  o.y = (y1 - mu) * rstd * g.y + bt.y;
  o.z = (y2 - mu) * rstd * g.z + bt.z;
  o.w = (y3 - mu) * rstd * g.w + bt.w;
  *(float4*)(y + base) = o;
}

// ---------------- host ----------------
extern "C" void kernel_launch(void* const* d_in, const int* in_sizes, int n_in,
                              void* d_out, int out_size, void* d_ws, size_t ws_size,
                              hipStream_t stream) {
  const float* x     = (const float*)d_in[0];
  const float* feats = (const float*)d_in[1];
  const float* dlog  = (const float*)d_in[2];
  const float* w_dp  = (const float*)d_in[3];
  const float* b_dp  = (const float*)d_in[4];
  const float* wql   = (const float*)d_in[5];
  const float* bql   = (const float*)d_in[6];
  const float* wqh   = (const float*)d_in[7];
  const float* bqh   = (const float*)d_in[8];
  const float* wol   = (const float*)d_in[9];
  const float* bol   = (const float*)d_in[10];
  const float* woh   = (const float*)d_in[11];
  const float* boh   = (const float*)d_in[12];
  const float* adj   = (const float*)d_in[13];
  const float* geow  = (const float*)d_in[14];
  const float* gamma = (const float*)d_in[15];
  const float* beta  = (const float*)d_in[16];

  char* ws = (char*)d_ws;
  constexpr size_t OFF_DW    = 0;
  constexpr size_t OFF_WLD   = 1024;
  constexpr size_t OFF_BLP   = 2048;
  constexpr size_t OFF_DEL   = 4096;        // 65536*4 -> ends 266240
  constexpr size_t OFF_WQLT  = 266240;      // 256*256*2 -> 397312
  constexpr size_t OFF_WQHT  = 397312;      // 768*192*2 -> 692224
  constexpr size_t OFF_KSP   = 692224;      // 8*256*32*4 -> 954368
  constexpr size_t OFF_MM    = 954368;      // 32*256*64*4 -> 3051520
  constexpr size_t OFF_LOW   = 3051520;     // 65536*192*2 = 24MB -> 28217344
  constexpr size_t OFF_ATTN  = 3051520;     // alias (low dead after GQKV), 16MB
  constexpr size_t OFF_KVP   = 19828736;    // alias low+16MB, 8MB
  constexpr size_t OFF_QF    = 28217344;    // 32MB -> 61771776
  constexpr size_t OFF_FEATB = OFF_QF;      // alias (featB dead after GLOW)
  constexpr size_t OFF_OUT   = OFF_QF;      // alias (qf dead after MATTN)
  constexpr size_t OFF_KF    = 61771776;    // 32MB -> 95326208
  constexpr size_t OFF_VP    = OFF_KF;      // alias (kf dead after kvreduce), 16MB
  constexpr size_t OFF_GEO2B = 78548992;    // alias kf+16MB, 8MB
  constexpr size_t OFF_V     = 95326208;    // 32MB -> 128880640
  constexpr size_t OFF_VP2T  = OFF_V;       // alias (v dead after MVP), 8MB

  float* dw      = (float*)(ws + OFF_DW);
  float* wl_d    = (float*)(ws + OFF_WLD);
  float* bl_p    = (float*)(ws + OFF_BLP);
  float* delayed = (float*)(ws + OFF_DEL);
  float* kvpart  = (float*)(ws + OFF_KVP);
  float* kspart  = (float*)(ws + OFF_KSP);
  float* Mm      = (float*)(ws + OFF_MM);
  u16* featB = (u16*)(ws + OFF_FEATB);
  u16* wqlT  = (u16*)(ws + OFF_WQLT);
  u16* wqhT  = (u16*)(ws + OFF_WQHT);
  u16* vp2t  = (u16*)(ws + OFF_VP2T);
  float* Vp  = (float*)(ws + OFF_VP);

  MArgs ml{};
  ml.delayed = delayed; ml.wl_d = wl_d; ml.bl_p = bl_p; ml.bqh = bqh;
  ml.low = (u16*)(ws + OFF_LOW);
  ml.qf  = (u16*)(ws + OFF_QF);
  ml.kf  = (u16*)(ws + OFF_KF);
  ml.v   = (u16*)(ws + OFF_V);
  ml.geo2b = (u16*)(ws + OFF_GEO2B);

  GArgs ga{};
  ga.wol = wol; ga.woh = woh; ga.bol = bol; ga.boh = boh; ga.geow = geow;
  ga.kspart = kspart; ga.Mm = Mm;
  ga.Vp = Vp; ga.attn = (float*)(ws + OFF_ATTN);
  ga.qf = ml.qf; ga.v = ml.v; ga.geo2b = ml.geo2b;
  ga.outbf = (u16*)(ws + OFF_OUT);

  prep_k<<<1, 256, 0, stream>>>(dlog, w_dp, b_dp, wql, bql, dw, wl_d, bl_p);
  delayed_k<<<256, 256, 0, stream>>>(x, dw, delayed);
  cvt_k<<<16384, 256, 0, stream>>>(feats, featB);            // features -> bf16
  tpose_k<<<256, 64, 0, stream>>>(wql, wqlT, 256, 192);      // wqlT [256pad][256]
  tpose_k<<<768, 64, 0, stream>>>(wqh, wqhT, 192, 768);      // wqhT [768][192]

  MArgs m0 = ml; m0.A = featB; m0.Bt = wqlT;
  mgemm_k<GLOW><<<dim3(2, 512), 256, 0, stream>>>(m0);       // low (bf16)

  MArgs m1 = ml; m1.A = ml.low; m1.Bt = wqhT;
  mgemm_k<GQKV><<<dim3(6, 512), 256, 0, stream>>>(m1);       // qf,kf,v (bf16)

  kvreduce_k<<<dim3(8, 8, 32), 64, 0, stream>>>(ml.kf, ml.v, kvpart, kspart);
  mmat_k<<<256, 64, 0, stream>>>(kvpart, wol, geow, Mm);

  gemm_k<MVP><<<dim3(1, 512), 256, 0, stream>>>(ga);         // Vp = v@Wl (f32)
  vpt_k<<<256, 256, 0, stream>>>(Vp, vp2t);                  // Vp2T bf16 [2048][2048]
  gemm_k<MATTN><<<dim3(1, 512), 256, 0, stream>>>(ga);       // attn (f32)

  MArgs m2 = ml; m2.A = nullptr; m2.Af32 = adj; m2.Bt = vp2t;
  mgemm_k<GGEO><<<dim3(16, 16), 256, 0, stream>>>(m2);       // geo2b = adj@Vp (bf16 MFMA)

  gemm_k<MFINAL><<<dim3(2, 512), 256, 0, stream>>>(ga);      // out = (attn+gb*geo+bol)@Woh
  ln_k<<<16384, 256, 0, stream>>>(ga.outbf, feats, gamma, beta, (float*)d_out);
  (void)in_sizes; (void)n_in; (void)out_size; (void)ws_size;
}

// Round 3
// 347.539 us; speedup vs baseline: 5.3146x; 1.6223x over previous
//
#include <hip/hip_runtime.h>
#include <hip/hip_bf16.h>
#include <stdint.h>

typedef unsigned short u16;
typedef float f4v __attribute__((ext_vector_type(4)));
typedef short s8v __attribute__((ext_vector_type(8)));

// B=32, T=64, N=2048, HID=256, HEADS=8, DH=32, BOT=64, MAX_LAG=7 ; rows = 65536

__device__ __forceinline__ float bf2f(u16 u) {
  union { float f; uint32_t i; } x; x.i = ((uint32_t)u) << 16; return x.f;
}
__device__ __forceinline__ u16 f2bf(float f) {
  uint32_t u = __float_as_uint(f);
  u = (u + 0x7FFFu + ((u >> 16) & 1u)) >> 16;
  return (u16)u;
}
__device__ __forceinline__ uint32_t pk2(float a, float b) {
  return (uint32_t)f2bf(a) | ((uint32_t)f2bf(b) << 16);
}
__device__ __forceinline__ void gload16(const void* g, void* l) {
  __builtin_amdgcn_global_load_lds((const __attribute__((address_space(1))) void*)g,
                                   (__attribute__((address_space(3))) void*)l, 16, 0, 0);
}

// ---------------- K0: prep (softmax(dw), folded delay weights) ----------------
__global__ void prep_k(const float* __restrict__ dlog, const float* __restrict__ w_dp,
                       const float* __restrict__ b_dp, const float* __restrict__ wql,
                       const float* __restrict__ bql,
                       float* __restrict__ dw, float* __restrict__ wl_d,
                       float* __restrict__ bl_p) {
  int t = threadIdx.x;
  if (t < 8) {
    float mx = dlog[0];
    for (int i = 1; i < 8; ++i) mx = fmaxf(mx, dlog[i]);
    float s = 0.f;
    for (int i = 0; i < 8; ++i) s += __expf(dlog[i] - mx);
    dw[t] = __expf(dlog[t] - mx) / s;
  }
  if (t < 192) {
    float s1 = 0.f, s2 = 0.f;
    for (int k = 0; k < 256; ++k) {
      float w = wql[k * 192 + t];
      s1 += w_dp[k] * w;
      s2 += b_dp[k] * w;
    }
    wl_d[t] = 0.1f * s1;
    bl_p[t] = bql[t] + 0.1f * s2;
  }
}

// ---------------- K1: delayed[b,n] ----------------
__global__ __launch_bounds__(256) void delayed_k(const float* __restrict__ x,
                                                 const float* __restrict__ dw,
                                                 float* __restrict__ delayed) {
  int r = blockIdx.x * 256 + threadIdx.x;
  int b = r >> 11, n = r & 2047;
  const float* xb = x + (size_t)b * 64 * 2048;
  float acc = 0.f;
#pragma unroll
  for (int tau = 0; tau < 8; ++tau) acc += dw[tau] * xb[(size_t)(63 - tau) * 2048 + n];
  delayed[r] = acc;
}

// out[n][k] = bf16(in[k][n]) for n<N else 0 ; out has K cols, grid = padN blocks
__global__ void tpose_k(const float* __restrict__ in, u16* __restrict__ out, int K, int N) {
  int n = blockIdx.x;
  for (int k = threadIdx.x; k < K; k += 64)
    out[(size_t)n * K + k] = f2bf(n < N ? in[(size_t)k * N + n] : 0.f);
}

// ---------------- bf16 MFMA GEMM template (128x128 tile, BK=32, 4 waves) ----------------
struct MArgs {
  const u16* A;        // bf16 row-major [M][LDA]
  const float* Af32;   // GLOW: features / GGEO: adj (fp32)
  const u16* Bt;       // bf16 row-major [Ncols][LDB]  (= B^T)
  const float* delayed; const float* wl_d; const float* bl_p;   // GLOW epilogue
  const float* bqh;                                             // GQKV epilogue
  const float* rden; const float* cvec;                         // GFIN
  const u16* geoA;                                              // GFIN A cols 256..319
  u16* low; u16* qf; u16* kf; u16* v; u16* geo2b; u16* vpt; u16* outb;
};

enum { GLOW = 0, GQKV = 1, GGEO = 2, GVP = 3, GFIN = 4 };

template <int MODE>
__global__ __launch_bounds__(256) void mgemm_k(MArgs ma) {
  constexpr int K   = (MODE == GLOW) ? 256 : (MODE == GQKV) ? 192 :
                      (MODE == GGEO) ? 2048 : (MODE == GVP) ? 256 : 320;
  constexpr int NC  = (MODE == GLOW) ? 192 : (MODE == GQKV) ? 768 :
                      (MODE == GGEO) ? 2048 : (MODE == GVP) ? 64 : 256;
  constexpr int LDA = (MODE == GQKV) ? 192 : (MODE == GGEO) ? 2048 : 256;
  constexpr int LDB = (MODE == GQKV) ? 192 : (MODE == GGEO) ? 2048 :
                      (MODE == GFIN) ? 320 : 256;

  __shared__ __align__(16) u16 Al[128 * 32];
  __shared__ __align__(16) u16 Bl[128 * 32];

  const int t = threadIdx.x;
  const int l = t & 63, w = t >> 6;
  const int wm = w >> 1, wn = w & 1;
  const int ct = blockIdx.x, rt = blockIdx.y;

  f4v acc[4][4] = {};

  for (int k0 = 0; k0 < K; k0 += 32) {
    __syncthreads();
#pragma unroll
    for (int s = 0; s < 2; ++s) {
      int c = s * 256 + t;
      int r = c >> 2, cc = c & 3;
      int g = cc ^ ((r >> 1) & 3);     // XOR chunk swizzle (involution)
      int row = rt * 128 + r;
      // ---- A tile [128][32] ----
      if constexpr (MODE == GLOW || MODE == GGEO) {
        const float* src = ma.Af32 + (size_t)row * LDA + k0 + g * 8;
        float4 x0 = *(const float4*)src;
        float4 x1 = *(const float4*)(src + 4);
        uint4 qq = {pk2(x0.x, x0.y), pk2(x0.z, x0.w), pk2(x1.x, x1.y), pk2(x1.z, x1.w)};
        *(uint4*)&Al[c * 8] = qq;
      } else if constexpr (MODE == GFIN) {
        if (k0 < 256) {
          int kk = k0 + g * 8;
          float sc = ma.rden[(size_t)row * 8 + (kk >> 5)];
          s8v qv = *(const s8v*)(ma.qf + (size_t)row * 256 + kk);
          uint32_t u0 = pk2(bf2f((u16)qv[0]) * sc, bf2f((u16)qv[1]) * sc);
          uint32_t u1 = pk2(bf2f((u16)qv[2]) * sc, bf2f((u16)qv[3]) * sc);
          uint32_t u2 = pk2(bf2f((u16)qv[4]) * sc, bf2f((u16)qv[5]) * sc);
          uint32_t u3 = pk2(bf2f((u16)qv[6]) * sc, bf2f((u16)qv[7]) * sc);
          uint4 qq = {u0, u1, u2, u3};
          *(uint4*)&Al[c * 8] = qq;
        } else {
          int n = row & 2047, bb = rt >> 4;
          gload16(ma.geoA + (size_t)n * 2048 + bb * 64 + (k0 - 256) + g * 8,
                  (char*)Al + (s * 4 + w) * 1024);
        }
      } else {
        gload16(ma.A + (size_t)row * LDA + k0 + g * 8, (char*)Al + (s * 4 + w) * 1024);
      }
      // ---- Bt tile [128][32] ----
      const u16* bbase = ma.Bt;
      if constexpr (MODE == GFIN) bbase += (size_t)(rt >> 4) * 256 * 320;
      gload16(bbase + (size_t)(ct * 128 + r) * LDB + k0 + g * 8,
              (char*)Bl + (s * 4 + w) * 1024);
    }
    __syncthreads();

    s8v fa[4], fb[4];
#pragma unroll
    for (int mr = 0; mr < 4; ++mr) {
      int ra = wm * 64 + mr * 16 + (l & 15);
      int ca = (l >> 4) ^ ((ra >> 1) & 3);
      fa[mr] = *(const s8v*)(Al + ra * 32 + ca * 8);
    }
#pragma unroll
    for (int nr = 0; nr < 4; ++nr) {
      int rb = wn * 64 + nr * 16 + (l & 15);
      int cb = (l >> 4) ^ ((rb >> 1) & 3);
      fb[nr] = *(const s8v*)(Bl + rb * 32 + cb * 8);
    }
#pragma unroll
    for (int mr = 0; mr < 4; ++mr)
#pragma unroll
      for (int nr = 0; nr < 4; ++nr)
        acc[mr][nr] = __builtin_amdgcn_mfma_f32_16x16x32_bf16(fa[mr], fb[nr], acc[mr][nr], 0, 0, 0);
  }

  // ---- epilogue ----  D: col = lane&15, row = (lane>>4)*4 + reg   [m89-verified]
  const int r0 = rt * 128 + wm * 64, c0 = ct * 128 + wn * 64;
  const int lr = (l >> 4) * 4, lc = l & 15;
#pragma unroll
  for (int mr = 0; mr < 4; ++mr)
#pragma unroll
    for (int nr = 0; nr < 4; ++nr) {
      int col = c0 + nr * 16 + lc;
      if constexpr (MODE == GLOW) {
        if (col < 192) {
          float wd = ma.wl_d[col], bp = ma.bl_p[col];
#pragma unroll
          for (int i = 0; i < 4; ++i) {
            int row = r0 + mr * 16 + lr + i;
            float val = acc[mr][nr][i] + ma.delayed[row] * wd + bp;
            ma.low[(size_t)row * 192 + col] = f2bf(val);
          }
        }
      } else if constexpr (MODE == GQKV) {
        int third = col >> 8, lc2 = col & 255;
        float bias = ma.bqh[col];
        u16* dst = (third == 0) ? ma.qf : (third == 1 ? ma.kf : ma.v);
#pragma unroll
        for (int i = 0; i < 4; ++i) {
          int row = r0 + mr * 16 + lr + i;
          float val = acc[mr][nr][i] + bias;
          if (third < 2) val = (val > 0.f) ? (val + 1.f) : __expf(val);
          dst[(size_t)row * 256 + lc2] = f2bf(val);
        }
      } else if constexpr (MODE == GGEO) {
#pragma unroll
        for (int i = 0; i < 4; ++i) {
          int row = r0 + mr * 16 + lr + i;
          ma.geo2b[(size_t)row * 2048 + col] = f2bf(acc[mr][nr][i]);
        }
      } else if constexpr (MODE == GVP) {
        if (wn == 0) {
          int d = nr * 16 + lc;                      // 0..63
          int n0 = (r0 + mr * 16 + lr) & 2047;
          int b = rt >> 4;
          ushort4 st = {f2bf(acc[mr][nr][0]), f2bf(acc[mr][nr][1]),
                        f2bf(acc[mr][nr][2]), f2bf(acc[mr][nr][3])};
          *(ushort4*)(ma.vpt + ((size_t)(b * 64 + d)) * 2048 + n0) = st;
        }
      } else {  // GFIN
        float cadd = ma.cvec[col];
#pragma unroll
        for (int i = 0; i < 4; ++i) {
          int row = r0 + mr * 16 + lr + i;
          ma.outb[(size_t)row * 256 + col] = f2bf(acc[mr][nr][i] + cadd);
        }
      }
    }
}

// ---------------- kv & ksum partial reduction (256 thr, 8 deterministic partials) ----------------
__global__ __launch_bounds__(256) void kvreduce_k(const u16* __restrict__ kf,
                                                  const u16* __restrict__ v,
                                                  float* __restrict__ kvpart,
                                                  float* __restrict__ kspart) {
  const int chunk = blockIdx.x, h = blockIdx.y, b = blockIdx.z;
  const int t = threadIdx.x, w = t >> 6, lane = t & 63;
  __shared__ float kfs[64][32], vs[64][32];
  const int d0 = (lane >> 3) * 4, e0 = (lane & 7) * 4;
  float acc[4][4] = {};
  float ks[4] = {0.f, 0.f, 0.f, 0.f};
  const int row0 = chunk * 1024;
  const int rr = t >> 2, c8 = (t & 3) * 8;
  for (int it = 0; it < 16; ++it) {
    __syncthreads();
    size_t g = ((size_t)(b * 2048 + row0 + it * 64 + rr)) * 256 + h * 32 + c8;
    s8v ku = *(const s8v*)(kf + g);
    s8v vu = *(const s8v*)(v + g);
#pragma unroll
    for (int j = 0; j < 8; ++j) {
      kfs[rr][c8 + j] = bf2f((u16)ku[j]);
      vs[rr][c8 + j] = bf2f((u16)vu[j]);
    }
    __syncthreads();
#pragma unroll
    for (int ri = 0; ri < 16; ++ri) {
      int r = w * 16 + ri;
      float4 a = *(const float4*)&kfs[r][d0];
      float4 bb = *(const float4*)&vs[r][e0];
      float aa[4] = {a.x, a.y, a.z, a.w};
      float bbv[4] = {bb.x, bb.y, bb.z, bb.w};
#pragma unroll
      for (int i = 0; i < 4; ++i)
#pragma unroll
        for (int j = 0; j < 4; ++j) acc[i][j] = fmaf(aa[i], bbv[j], acc[i][j]);
      if (e0 == 0) {
        ks[0] += aa[0]; ks[1] += aa[1]; ks[2] += aa[2]; ks[3] += aa[3];
      }
    }
  }
  const int p = chunk * 4 + w;
  float* kvp = kvpart + ((size_t)p * 256 + b * 8 + h) * 1024;
#pragma unroll
  for (int i = 0; i < 4; ++i)
#pragma unroll
    for (int j = 0; j < 4; ++j) kvp[(d0 + i) * 32 + e0 + j] = acc[i][j];
  if (e0 == 0) {
    float* ksp = kspart + ((size_t)p * 256 + b * 8 + h) * 32;
#pragma unroll
    for (int i = 0; i < 4; ++i) ksp[d0 + i] = ks[i];
  }
}

// ---------------- M[b,h] = (1-gb) * kv[b,h] @ Wl_h ----------------
__global__ __launch_bounds__(64) void mmat_k(const float* __restrict__ kvpart,
                                             const float* __restrict__ wol,
                                             const float* __restrict__ geow,
                                             float* __restrict__ Mm) {
  const int bh = blockIdx.x;
  const int h = bh & 7, b = bh >> 3;
  const int c = threadIdx.x;
  __shared__ float kvs[32][32];
  for (int i = c; i < 1024; i += 64) {
    float s = 0.f;
#pragma unroll
    for (int p = 0; p < 8; ++p) s += kvpart[(size_t)(p * 256 + bh) * 1024 + i];
    kvs[i >> 5][i & 31] = s;
  }
  __syncthreads();
  float one_m = 1.f - 1.f / (1.f + __expf(-geow[0]));
  float acc[32];
#pragma unroll
  for (int d = 0; d < 32; ++d) acc[d] = 0.f;
  for (int e = 0; e < 32; ++e) {
    float w = wol[(size_t)(h * 32 + e) * 64 + c];
#pragma unroll
    for (int d = 0; d < 32; ++d) acc[d] = fmaf(kvs[d][e], w, acc[d]);
  }
  float* mp = Mm + (size_t)b * 16384 + (size_t)h * 32 * 64 + c;
#pragma unroll
  for (int d = 0; d < 32; ++d) mp[d * 64] = one_m * acc[d];
}

// ---------------- B2t[b][c][320] = [ (Mm[b]@Woh)^T ; gb*Woh^T ] ; cvec ----------------
__global__ __launch_bounds__(256) void bprep_k(const float* __restrict__ Mm,
                                               const float* __restrict__ woh,
                                               const float* __restrict__ bol,
                                               const float* __restrict__ boh,
                                               const float* __restrict__ geow,
                                               u16* __restrict__ B2t,
                                               float* __restrict__ cvec) {
  const int kt = blockIdx.x, b = blockIdx.y;   // kt<4 (64 k each)
  const int c = threadIdx.x;                   // 0..255
  __shared__ float Ms[64][64];
#pragma unroll
  for (int i = 0; i < 16; ++i) {
    int flat = c + i * 256;
    int kk = flat >> 6, e = flat & 63;
    Ms[kk][e] = Mm[(size_t)b * 16384 + (size_t)(kt * 64 + kk) * 64 + e];
  }
  __syncthreads();
  float wcol[64];
#pragma unroll
  for (int e = 0; e < 64; ++e) wcol[e] = woh[(size_t)e * 256 + c];
  u16* dst = B2t + ((size_t)b * 256 + c) * 320;
  for (int kk = 0; kk < 64; ++kk) {
    float s = 0.f;
#pragma unroll
    for (int e = 0; e < 64; ++e) s = fmaf(Ms[kk][e], wcol[e], s);
    dst[kt * 64 + kk] = f2bf(s);
  }
  if (kt == 0) {
    float gb = 1.f / (1.f + __expf(-geow[0]));
#pragma unroll
    for (int d = 0; d < 64; ++d) dst[256 + d] = f2bf(gb * wcol[d]);
    if (b == 0) {
      float s = boh[c];
#pragma unroll
      for (int d = 0; d < 64; ++d) s = fmaf(bol[d], wcol[d], s);
      cvec[c] = s;
    }
  }
}

// ---------------- rden[row][h] = 1/(qf_row_h . (ksum_h+1e-8) + 1e-8) ----------------
__global__ __launch_bounds__(256) void rden_k(const u16* __restrict__ qf,
                                              const float* __restrict__ kspart,
                                              float* __restrict__ rden) {
  const int t = threadIdx.x;
  const int b = (blockIdx.x * 16) >> 11;
  __shared__ float ksumf[256];
  {
    int h = t >> 5, e = t & 31;
    float s = 0.f;
#pragma unroll
    for (int p = 0; p < 8; ++p) s += kspart[(size_t)(p * 256 + b * 8 + h) * 32 + e];
    ksumf[t] = s + 1e-8f;
  }
  __syncthreads();
  const int row = blockIdx.x * 16 + (t >> 4);
  const int c0 = (t & 15) * 16;
  s8v q0 = *(const s8v*)(qf + (size_t)row * 256 + c0);
  s8v q1 = *(const s8v*)(qf + (size_t)row * 256 + c0 + 8);
  float part = 0.f;
#pragma unroll
  for (int j = 0; j < 8; ++j) part = fmaf(bf2f((u16)q0[j]), ksumf[c0 + j], part);
#pragma unroll
  for (int j = 0; j < 8; ++j) part = fmaf(bf2f((u16)q1[j]), ksumf[c0 + 8 + j], part);
  float den = part + __shfl_xor(part, 1);
  if ((t & 1) == 0) rden[(size_t)row * 8 + (c0 >> 5)] = 1.f / (den + 1e-8f);
}

// ---------------- residual + LayerNorm ----------------
__global__ __launch_bounds__(256) void ln_k(const u16* __restrict__ outbf,
                                            const float* __restrict__ features,
                                            const float* __restrict__ gamma,
                                            const float* __restrict__ beta,
                                            float* __restrict__ y) {
  int wid = threadIdx.x >> 6, lane = threadIdx.x & 63;
  int row = blockIdx.x * 4 + wid;
  size_t base = (size_t)row * 256 + lane * 4;
  ushort4 ob = *(const ushort4*)(outbf + base);
  float4 ft = *(const float4*)(features + base);
  float y0 = bf2f(ob.x) + ft.x;
  float y1 = bf2f(ob.y) + ft.y;
  float y2 = bf2f(ob.z) + ft.z;
  float y3 = bf2f(ob.w) + ft.w;
  float s1 = y0 + y1 + y2 + y3;
  float s2 = y0 * y0 + y1 * y1 + y2 * y2 + y3 * y3;
#pragma unroll
  for (int off = 32; off; off >>= 1) {
    s1 += __shfl_xor(s1, off);
    s2 += __shfl_xor(s2, off);
  }
  float mu = s1 * (1.f / 256.f);
  float var = s2 * (1.f / 256.f) - mu * mu;
  float rstd = rsqrtf(fmaxf(var, 0.f) + 1e-5f);
  float4 g = *(const float4*)(gamma + lane * 4);
  float4 bt = *(const float4*)(beta + lane * 4);
  float4 o;
  o.x = (y0 - mu) * rstd * g.x + bt.x;
  o.y = (y1 - mu) * rstd * g.y + bt.y;
  o.z = (y2 - mu) * rstd * g.z + bt.z;
  o.w = (y3 - mu) * rstd * g.w + bt.w;
  *(float4*)(y + base) = o;
}

// ---------------- host ----------------
extern "C" void kernel_launch(void* const* d_in, const int* in_sizes, int n_in,
                              void* d_out, int out_size, void* d_ws, size_t ws_size,
                              hipStream_t stream) {
  const float* x     = (const float*)d_in[0];
  const float* feats = (const float*)d_in[1];
  const float* dlog  = (const float*)d_in[2];
  const float* w_dp  = (const float*)d_in[3];
  const float* b_dp  = (const float*)d_in[4];
  const float* wql   = (const float*)d_in[5];
  const float* bql   = (const float*)d_in[6];
  const float* wqh   = (const float*)d_in[7];
  const float* bqh   = (const float*)d_in[8];
  const float* wol   = (const float*)d_in[9];
  const float* bol   = (const float*)d_in[10];
  const float* woh   = (const float*)d_in[11];
  const float* boh   = (const float*)d_in[12];
  const float* adj   = (const float*)d_in[13];
  const float* geow  = (const float*)d_in[14];
  const float* gamma = (const float*)d_in[15];
  const float* beta  = (const float*)d_in[16];

  char* ws = (char*)d_ws;
  // total 136,290,304 B  (<= 136,843,264 proven available in round 1)
  constexpr size_t OFF_DW    = 0;
  constexpr size_t OFF_WLD   = 1024;
  constexpr size_t OFF_BLP   = 2048;
  constexpr size_t OFF_CVEC  = 4096;
  constexpr size_t OFF_DEL   = 8192;        // 256KB -> 270336
  constexpr size_t OFF_WQLT  = 270336;      // 256*256*2 -> 401408
  constexpr size_t OFF_WQHT  = 401408;      // 768*192*2 -> 696320
  constexpr size_t OFF_WOLT  = 696320;      // 128*256*2 -> 761856
  constexpr size_t OFF_KSP   = 761856;      // 8*256*32*4 -> 1024000
  constexpr size_t OFF_RDEN  = 1024000;     // 65536*8*4 -> 3121152
  constexpr size_t OFF_MM    = 3121152;     // 32*256*64*4 -> 5218304
  constexpr size_t OFF_B2T   = 5218304;     // 32*256*320*2 -> 10461184
  constexpr size_t OFF_LOW   = 10461184;    // 24MB -> 35627008 [dead after GQKV]
  constexpr size_t OFF_KVP   = OFF_LOW;               // 8MB [kvreduce..mmat]
  constexpr size_t OFF_VPT   = OFF_LOW + 8388608;     // 8MB [GVP..GGEO]
  constexpr size_t OFF_GEO2B = OFF_LOW + 16777216;    // 8MB [GGEO..GFIN]
  constexpr size_t OFF_QF    = 35627008;    // 32MB -> 69181440 [GQKV..GFIN]
  constexpr size_t OFF_KF    = 69181440;    // 32MB -> 102735872 [GQKV..kvreduce]
  constexpr size_t OFF_OUT   = OFF_KF;      // [GFIN..ln]
  constexpr size_t OFF_V     = 102735872;   // 32MB -> 136290304 [GQKV..GVP]

  float* dw      = (float*)(ws + OFF_DW);
  float* wl_d    = (float*)(ws + OFF_WLD);
  float* bl_p    = (float*)(ws + OFF_BLP);
  float* cvec    = (float*)(ws + OFF_CVEC);
  float* delayed = (float*)(ws + OFF_DEL);
  float* kvpart  = (float*)(ws + OFF_KVP);
  float* kspart  = (float*)(ws + OFF_KSP);
  float* rden    = (float*)(ws + OFF_RDEN);
  float* Mm      = (float*)(ws + OFF_MM);
  u16* wqlT = (u16*)(ws + OFF_WQLT);
  u16* wqhT = (u16*)(ws + OFF_WQHT);
  u16* wolT = (u16*)(ws + OFF_WOLT);
  u16* B2t  = (u16*)(ws + OFF_B2T);

  MArgs ma{};
  ma.delayed = delayed; ma.wl_d = wl_d; ma.bl_p = bl_p; ma.bqh = bqh;
  ma.rden = rden; ma.cvec = cvec;
  ma.low = (u16*)(ws + OFF_LOW);
  ma.qf  = (u16*)(ws + OFF_QF);
  ma.kf  = (u16*)(ws + OFF_KF);
  ma.v   = (u16*)(ws + OFF_V);
  ma.geo2b = (u16*)(ws + OFF_GEO2B);
  ma.vpt   = (u16*)(ws + OFF_VPT);
  ma.outb  = (u16*)(ws + OFF_OUT);
  ma.geoA  = ma.geo2b;

  prep_k<<<1, 256, 0, stream>>>(dlog, w_dp, b_dp, wql, bql, dw, wl_d, bl_p);
  delayed_k<<<256, 256, 0, stream>>>(x, dw, delayed);
  tpose_k<<<256, 64, 0, stream>>>(wql, wqlT, 256, 192);
  tpose_k<<<768, 64, 0, stream>>>(wqh, wqhT, 192, 768);
  tpose_k<<<128, 64, 0, stream>>>(wol, wolT, 256, 64);

  MArgs m0 = ma; m0.Af32 = feats; m0.Bt = wqlT;
  mgemm_k<GLOW><<<dim3(2, 512), 256, 0, stream>>>(m0);       // low (bf16)

  MArgs m1 = ma; m1.A = ma.low; m1.Bt = wqhT;
  mgemm_k<GQKV><<<dim3(6, 512), 256, 0, stream>>>(m1);       // qf,kf,v (bf16)

  kvreduce_k<<<dim3(2, 8, 32), 256, 0, stream>>>(ma.kf, ma.v, kvpart, kspart);
  mmat_k<<<256, 64, 0, stream>>>(kvpart, wol, geow, Mm);
  bprep_k<<<dim3(4, 32), 256, 0, stream>>>(Mm, woh, bol, boh, geow, B2t, cvec);
  rden_k<<<4096, 256, 0, stream>>>(ma.qf, kspart, rden);

  MArgs m2 = ma; m2.A = ma.v; m2.Bt = wolT;
  mgemm_k<GVP><<<dim3(1, 512), 256, 0, stream>>>(m2);        // vpt = (v@Wol)^T bf16

  MArgs m3 = ma; m3.Af32 = adj; m3.Bt = ma.vpt;
  mgemm_k<GGEO><<<dim3(16, 16), 256, 0, stream>>>(m3);       // geo2b = adj@Vp (bf16)

  MArgs m4 = ma; m4.Bt = B2t;
  mgemm_k<GFIN><<<dim3(2, 512), 256, 0, stream>>>(m4);       // out = qs@MW + geo@gbWoh + cvec

  ln_k<<<16384, 256, 0, stream>>>(ma.outb, feats, gamma, beta, (float*)d_out);
  (void)in_sizes; (void)n_in; (void)out_size; (void)ws_size;
}

// Round 4
// 314.886 us; speedup vs baseline: 5.8657x; 1.1037x over previous
//
#include <hip/hip_runtime.h>
#include <hip/hip_bf16.h>
#include <stdint.h>

typedef unsigned short u16;
typedef float f4v __attribute__((ext_vector_type(4)));
typedef short s8v __attribute__((ext_vector_type(8)));

// B=32, T=64, N=2048, HID=256, HEADS=8, DH=32, BOT=64, MAX_LAG=7 ; rows = 65536

__device__ __forceinline__ float bf2f(u16 u) {
  union { float f; uint32_t i; } x; x.i = ((uint32_t)u) << 16; return x.f;
}
__device__ __forceinline__ u16 f2bf(float f) {
  uint32_t u = __float_as_uint(f);
  u = (u + 0x7FFFu + ((u >> 16) & 1u)) >> 16;
  return (u16)u;
}
__device__ __forceinline__ uint32_t pk2(float a, float b) {
  return (uint32_t)f2bf(a) | ((uint32_t)f2bf(b) << 16);
}
__device__ __forceinline__ void gload16(const void* g, void* l) {
  __builtin_amdgcn_global_load_lds((const __attribute__((address_space(1))) void*)g,
                                   (__attribute__((address_space(3))) void*)l, 16, 0, 0);
}

// ---------------- K0: prep (softmax(dw), folded delay weights) ----------------
__global__ void prep_k(const float* __restrict__ dlog, const float* __restrict__ w_dp,
                       const float* __restrict__ b_dp, const float* __restrict__ wql,
                       const float* __restrict__ bql,
                       float* __restrict__ dw, float* __restrict__ wl_d,
                       float* __restrict__ bl_p) {
  int t = threadIdx.x;
  if (t < 8) {
    float mx = dlog[0];
    for (int i = 1; i < 8; ++i) mx = fmaxf(mx, dlog[i]);
    float s = 0.f;
    for (int i = 0; i < 8; ++i) s += __expf(dlog[i] - mx);
    dw[t] = __expf(dlog[t] - mx) / s;
  }
  if (t < 192) {
    float s1 = 0.f, s2 = 0.f;
    for (int k = 0; k < 256; ++k) {
      float w = wql[k * 192 + t];
      s1 += w_dp[k] * w;
      s2 += b_dp[k] * w;
    }
    wl_d[t] = 0.1f * s1;
    bl_p[t] = bql[t] + 0.1f * s2;
  }
}

// ---------------- K1: delayed[b,n] ----------------
__global__ __launch_bounds__(256) void delayed_k(const float* __restrict__ x,
                                                 const float* __restrict__ dw,
                                                 float* __restrict__ delayed) {
  int r = blockIdx.x * 256 + threadIdx.x;
  int b = r >> 11, n = r & 2047;
  const float* xb = x + (size_t)b * 64 * 2048;
  float acc = 0.f;
#pragma unroll
  for (int tau = 0; tau < 8; ++tau) acc += dw[tau] * xb[(size_t)(63 - tau) * 2048 + n];
  delayed[r] = acc;
}

// out[n][k] = bf16(in[k][n]) for n<N else 0 ; out has K cols, grid = padN blocks
__global__ void tpose_k(const float* __restrict__ in, u16* __restrict__ out, int K, int N) {
  int n = blockIdx.x;
  for (int k = threadIdx.x; k < K; k += 64)
    out[(size_t)n * K + k] = f2bf(n < N ? in[(size_t)k * N + n] : 0.f);
}

// ---------------- adj fp32 -> bf16 (8 elems/thread) ----------------
__global__ __launch_bounds__(256) void cvtadj_k(const float* __restrict__ in,
                                                u16* __restrict__ out) {
  size_t i = ((size_t)blockIdx.x * 256 + threadIdx.x) * 8;
  float4 a = *(const float4*)(in + i);
  float4 b = *(const float4*)(in + i + 4);
  uint4 q = {pk2(a.x, a.y), pk2(a.z, a.w), pk2(b.x, b.y), pk2(b.z, b.w)};
  *(uint4*)(out + i) = q;
}

// ---------------- sum 4 bf16 split-K partials -> geo2b ----------------
__global__ __launch_bounds__(256) void georeduce_k(const u16* __restrict__ part,
                                                   u16* __restrict__ geo2b) {
  size_t i = ((size_t)blockIdx.x * 256 + threadIdx.x) * 8;
  s8v p0 = *(const s8v*)(part + i);
  s8v p1 = *(const s8v*)(part + 4194304 + i);
  s8v p2 = *(const s8v*)(part + 8388608 + i);
  s8v p3 = *(const s8v*)(part + 12582912 + i);
  uint32_t q[4];
#pragma unroll
  for (int j = 0; j < 4; ++j) {
    float lo = bf2f((u16)p0[2 * j]) + bf2f((u16)p1[2 * j]) +
               bf2f((u16)p2[2 * j]) + bf2f((u16)p3[2 * j]);
    float hi = bf2f((u16)p0[2 * j + 1]) + bf2f((u16)p1[2 * j + 1]) +
               bf2f((u16)p2[2 * j + 1]) + bf2f((u16)p3[2 * j + 1]);
    q[j] = pk2(lo, hi);
  }
  uint4 qq = {q[0], q[1], q[2], q[3]};
  *(uint4*)(geo2b + i) = qq;
}

// ---------------- bf16 MFMA GEMM template (128x128 tile, BK=32, 4 waves) ----------------
struct MArgs {
  const u16* A;        // bf16 row-major [M][LDA]
  const float* Af32;   // GLOW: features (fp32)
  const u16* Bt;       // bf16 row-major [Ncols][LDB]  (= B^T)
  const u16* adjb;     // GGEO A (bf16)
  const float* delayed; const float* wl_d; const float* bl_p;   // GLOW epilogue
  const float* bqh;                                             // GQKV epilogue
  const float* rden; const float* cvec;                         // GFIN
  const u16* geoA;                                              // GFIN A cols 256..319
  u16* low; u16* qf; u16* kf; u16* v; u16* geo2b; u16* vpt; u16* outb;
  u16* geopart;                                                 // GGEO split-K partials
};

enum { GLOW = 0, GQKV = 1, GGEO = 2, GVP = 3, GFIN = 4 };

template <int MODE>
__global__ __launch_bounds__(256) void mgemm_k(MArgs ma) {
  constexpr int KLOOP = (MODE == GLOW) ? 256 : (MODE == GQKV) ? 192 :
                        (MODE == GGEO) ? 512 : (MODE == GVP) ? 256 : 320;
  constexpr int NC  = (MODE == GLOW) ? 192 : (MODE == GQKV) ? 768 :
                      (MODE == GGEO) ? 2048 : (MODE == GVP) ? 64 : 256;
  constexpr int LDA = (MODE == GQKV) ? 192 : (MODE == GGEO) ? 2048 : 256;
  constexpr int LDB = (MODE == GQKV) ? 192 : (MODE == GGEO) ? 2048 :
                      (MODE == GFIN) ? 320 : 256;

  __shared__ __align__(16) u16 Al[128 * 32];
  __shared__ __align__(16) u16 Bl[128 * 32];

  const int t = threadIdx.x;
  const int l = t & 63, w = t >> 6;
  const int wm = w >> 1, wn = w & 1;
  const int ct = blockIdx.x, rt = blockIdx.y;
  const int bz = (MODE == GGEO) ? blockIdx.z : 0;
  const int kbase = (MODE == GGEO) ? bz * 512 : 0;

  f4v acc[4][4] = {};

  for (int k0 = 0; k0 < KLOOP; k0 += 32) {
    __syncthreads();
#pragma unroll
    for (int s = 0; s < 2; ++s) {
      int c = s * 256 + t;
      int r = c >> 2, cc = c & 3;
      int g = cc ^ ((r >> 1) & 3);     // XOR chunk swizzle (involution)
      int row = rt * 128 + r;
      int kg = kbase + k0 + g * 8;
      // ---- A tile [128][32] ----
      if constexpr (MODE == GLOW) {
        const float* src = ma.Af32 + (size_t)row * LDA + kg;
        float4 x0 = *(const float4*)src;
        float4 x1 = *(const float4*)(src + 4);
        uint4 qq = {pk2(x0.x, x0.y), pk2(x0.z, x0.w), pk2(x1.x, x1.y), pk2(x1.z, x1.w)};
        *(uint4*)&Al[c * 8] = qq;
      } else if constexpr (MODE == GGEO) {
        gload16(ma.adjb + (size_t)row * 2048 + kg, (char*)Al + (s * 4 + w) * 1024);
      } else if constexpr (MODE == GFIN) {
        if (k0 < 256) {
          float sc = ma.rden[(size_t)row * 8 + (kg >> 5)];
          s8v qv = *(const s8v*)(ma.qf + (size_t)row * 256 + kg);
          uint32_t u0 = pk2(bf2f((u16)qv[0]) * sc, bf2f((u16)qv[1]) * sc);
          uint32_t u1 = pk2(bf2f((u16)qv[2]) * sc, bf2f((u16)qv[3]) * sc);
          uint32_t u2 = pk2(bf2f((u16)qv[4]) * sc, bf2f((u16)qv[5]) * sc);
          uint32_t u3 = pk2(bf2f((u16)qv[6]) * sc, bf2f((u16)qv[7]) * sc);
          uint4 qq = {u0, u1, u2, u3};
          *(uint4*)&Al[c * 8] = qq;
        } else {
          int n = row & 2047, bb = rt >> 4;
          gload16(ma.geoA + (size_t)n * 2048 + bb * 64 + (kg - 256),
                  (char*)Al + (s * 4 + w) * 1024);
        }
      } else {
        gload16(ma.A + (size_t)row * LDA + kg, (char*)Al + (s * 4 + w) * 1024);
      }
      // ---- Bt tile [128][32] ----
      const u16* bbase = ma.Bt;
      if constexpr (MODE == GFIN) bbase += (size_t)(rt >> 4) * 256 * 320;
      gload16(bbase + (size_t)(ct * 128 + r) * LDB + kg,
              (char*)Bl + (s * 4 + w) * 1024);
    }
    __syncthreads();

    s8v fa[4], fb[4];
#pragma unroll
    for (int mr = 0; mr < 4; ++mr) {
      int ra = wm * 64 + mr * 16 + (l & 15);
      int ca = (l >> 4) ^ ((ra >> 1) & 3);
      fa[mr] = *(const s8v*)(Al + ra * 32 + ca * 8);
    }
#pragma unroll
    for (int nr = 0; nr < 4; ++nr) {
      int rb = wn * 64 + nr * 16 + (l & 15);
      int cb = (l >> 4) ^ ((rb >> 1) & 3);
      fb[nr] = *(const s8v*)(Bl + rb * 32 + cb * 8);
    }
#pragma unroll
    for (int mr = 0; mr < 4; ++mr)
#pragma unroll
      for (int nr = 0; nr < 4; ++nr)
        acc[mr][nr] = __builtin_amdgcn_mfma_f32_16x16x32_bf16(fa[mr], fb[nr], acc[mr][nr], 0, 0, 0);
  }

  // ---- epilogue ----  D: col = lane&15, row = (lane>>4)*4 + reg   [m89-verified]
  const int r0 = rt * 128 + wm * 64, c0 = ct * 128 + wn * 64;
  const int lr = (l >> 4) * 4, lc = l & 15;
#pragma unroll
  for (int mr = 0; mr < 4; ++mr)
#pragma unroll
    for (int nr = 0; nr < 4; ++nr) {
      int col = c0 + nr * 16 + lc;
      if constexpr (MODE == GLOW) {
        if (col < 192) {
          float wd = ma.wl_d[col], bp = ma.bl_p[col];
#pragma unroll
          for (int i = 0; i < 4; ++i) {
            int row = r0 + mr * 16 + lr + i;
            float val = acc[mr][nr][i] + ma.delayed[row] * wd + bp;
            ma.low[(size_t)row * 192 + col] = f2bf(val);
          }
        }
      } else if constexpr (MODE == GQKV) {
        int third = col >> 8, lc2 = col & 255;
        float bias = ma.bqh[col];
        u16* dst = (third == 0) ? ma.qf : (third == 1 ? ma.kf : ma.v);
#pragma unroll
        for (int i = 0; i < 4; ++i) {
          int row = r0 + mr * 16 + lr + i;
          float val = acc[mr][nr][i] + bias;
          if (third < 2) val = (val > 0.f) ? (val + 1.f) : __expf(val);
          dst[(size_t)row * 256 + lc2] = f2bf(val);
        }
      } else if constexpr (MODE == GGEO) {
        u16* dst = ma.geopart + (size_t)bz * 4194304;
#pragma unroll
        for (int i = 0; i < 4; ++i) {
          int row = r0 + mr * 16 + lr + i;
          dst[(size_t)row * 2048 + col] = f2bf(acc[mr][nr][i]);
        }
      } else if constexpr (MODE == GVP) {
        if (wn == 0) {
          int d = nr * 16 + lc;                      // 0..63
          int n0 = (r0 + mr * 16 + lr) & 2047;
          int b = rt >> 4;
          ushort4 st = {f2bf(acc[mr][nr][0]), f2bf(acc[mr][nr][1]),
                        f2bf(acc[mr][nr][2]), f2bf(acc[mr][nr][3])};
          *(ushort4*)(ma.vpt + ((size_t)(b * 64 + d)) * 2048 + n0) = st;
        }
      } else {  // GFIN
        float cadd = ma.cvec[col];
#pragma unroll
        for (int i = 0; i < 4; ++i) {
          int row = r0 + mr * 16 + lr + i;
          ma.outb[(size_t)row * 256 + col] = f2bf(acc[mr][nr][i] + cadd);
        }
      }
    }
}

// ---------------- kv & ksum partial reduction (256 thr, 8 deterministic partials) ----------------
__global__ __launch_bounds__(256) void kvreduce_k(const u16* __restrict__ kf,
                                                  const u16* __restrict__ v,
                                                  float* __restrict__ kvpart,
                                                  float* __restrict__ kspart) {
  const int chunk = blockIdx.x, h = blockIdx.y, b = blockIdx.z;
  const int t = threadIdx.x, w = t >> 6, lane = t & 63;
  __shared__ float kfs[64][32], vs[64][32];
  const int d0 = (lane >> 3) * 4, e0 = (lane & 7) * 4;
  float acc[4][4] = {};
  float ks[4] = {0.f, 0.f, 0.f, 0.f};
  const int row0 = chunk * 1024;
  const int rr = t >> 2, c8 = (t & 3) * 8;
  for (int it = 0; it < 16; ++it) {
    __syncthreads();
    size_t g = ((size_t)(b * 2048 + row0 + it * 64 + rr)) * 256 + h * 32 + c8;
    s8v ku = *(const s8v*)(kf + g);
    s8v vu = *(const s8v*)(v + g);
#pragma unroll
    for (int j = 0; j < 8; ++j) {
      kfs[rr][c8 + j] = bf2f((u16)ku[j]);
      vs[rr][c8 + j] = bf2f((u16)vu[j]);
    }
    __syncthreads();
#pragma unroll
    for (int ri = 0; ri < 16; ++ri) {
      int r = w * 16 + ri;
      float4 a = *(const float4*)&kfs[r][d0];
      float4 bb = *(const float4*)&vs[r][e0];
      float aa[4] = {a.x, a.y, a.z, a.w};
      float bbv[4] = {bb.x, bb.y, bb.z, bb.w};
#pragma unroll
      for (int i = 0; i < 4; ++i)
#pragma unroll
        for (int j = 0; j < 4; ++j) acc[i][j] = fmaf(aa[i], bbv[j], acc[i][j]);
      if (e0 == 0) {
        ks[0] += aa[0]; ks[1] += aa[1]; ks[2] += aa[2]; ks[3] += aa[3];
      }
    }
  }
  const int p = chunk * 4 + w;
  float* kvp = kvpart + ((size_t)p * 256 + b * 8 + h) * 1024;
#pragma unroll
  for (int i = 0; i < 4; ++i)
#pragma unroll
    for (int j = 0; j < 4; ++j) kvp[(d0 + i) * 32 + e0 + j] = acc[i][j];
  if (e0 == 0) {
    float* ksp = kspart + ((size_t)p * 256 + b * 8 + h) * 32;
#pragma unroll
    for (int i = 0; i < 4; ++i) ksp[d0 + i] = ks[i];
  }
}

// ---------------- M[b,h] = (1-gb) * kv[b,h] @ Wl_h ----------------
__global__ __launch_bounds__(64) void mmat_k(const float* __restrict__ kvpart,
                                             const float* __restrict__ wol,
                                             const float* __restrict__ geow,
                                             float* __restrict__ Mm) {
  const int bh = blockIdx.x;
  const int h = bh & 7, b = bh >> 3;
  const int c = threadIdx.x;
  __shared__ float kvs[32][32];
  for (int i = c; i < 1024; i += 64) {
    float s = 0.f;
#pragma unroll
    for (int p = 0; p < 8; ++p) s += kvpart[(size_t)(p * 256 + bh) * 1024 + i];
    kvs[i >> 5][i & 31] = s;
  }
  __syncthreads();
  float one_m = 1.f - 1.f / (1.f + __expf(-geow[0]));
  float acc[32];
#pragma unroll
  for (int d = 0; d < 32; ++d) acc[d] = 0.f;
  for (int e = 0; e < 32; ++e) {
    float w = wol[(size_t)(h * 32 + e) * 64 + c];
#pragma unroll
    for (int d = 0; d < 32; ++d) acc[d] = fmaf(kvs[d][e], w, acc[d]);
  }
  float* mp = Mm + (size_t)b * 16384 + (size_t)h * 32 * 64 + c;
#pragma unroll
  for (int d = 0; d < 32; ++d) mp[d * 64] = one_m * acc[d];
}

// ---------------- B2t[b][c][320] = [ (Mm[b]@Woh)^T ; gb*Woh^T ] ; cvec ----------------
__global__ __launch_bounds__(256) void bprep_k(const float* __restrict__ Mm,
                                               const float* __restrict__ woh,
                                               const float* __restrict__ bol,
                                               const float* __restrict__ boh,
                                               const float* __restrict__ geow,
                                               u16* __restrict__ B2t,
                                               float* __restrict__ cvec) {
  const int kt = blockIdx.x, b = blockIdx.y;   // kt<4 (64 k each)
  const int c = threadIdx.x;                   // 0..255
  __shared__ float Ms[64][64];
#pragma unroll
  for (int i = 0; i < 16; ++i) {
    int flat = c + i * 256;
    int kk = flat >> 6, e = flat & 63;
    Ms[kk][e] = Mm[(size_t)b * 16384 + (size_t)(kt * 64 + kk) * 64 + e];
  }
  __syncthreads();
  float wcol[64];
#pragma unroll
  for (int e = 0; e < 64; ++e) wcol[e] = woh[(size_t)e * 256 + c];
  u16* dst = B2t + ((size_t)b * 256 + c) * 320;
  for (int kk = 0; kk < 64; ++kk) {
    float s = 0.f;
#pragma unroll
    for (int e = 0; e < 64; ++e) s = fmaf(Ms[kk][e], wcol[e], s);
    dst[kt * 64 + kk] = f2bf(s);
  }
  if (kt == 0) {
    float gb = 1.f / (1.f + __expf(-geow[0]));
#pragma unroll
    for (int d = 0; d < 64; ++d) dst[256 + d] = f2bf(gb * wcol[d]);
    if (b == 0) {
      float s = boh[c];
#pragma unroll
      for (int d = 0; d < 64; ++d) s = fmaf(bol[d], wcol[d], s);
      cvec[c] = s;
    }
  }
}

// ---------------- rden[row][h] = 1/(qf_row_h . (ksum_h+1e-8) + 1e-8) ----------------
__global__ __launch_bounds__(256) void rden_k(const u16* __restrict__ qf,
                                              const float* __restrict__ kspart,
                                              float* __restrict__ rden) {
  const int t = threadIdx.x;
  const int b = (blockIdx.x * 16) >> 11;
  __shared__ float ksumf[256];
  {
    int h = t >> 5, e = t & 31;
    float s = 0.f;
#pragma unroll
    for (int p = 0; p < 8; ++p) s += kspart[(size_t)(p * 256 + b * 8 + h) * 32 + e];
    ksumf[t] = s + 1e-8f;
  }
  __syncthreads();
  const int row = blockIdx.x * 16 + (t >> 4);
  const int c0 = (t & 15) * 16;
  s8v q0 = *(const s8v*)(qf + (size_t)row * 256 + c0);
  s8v q1 = *(const s8v*)(qf + (size_t)row * 256 + c0 + 8);
  float part = 0.f;
#pragma unroll
  for (int j = 0; j < 8; ++j) part = fmaf(bf2f((u16)q0[j]), ksumf[c0 + j], part);
#pragma unroll
  for (int j = 0; j < 8; ++j) part = fmaf(bf2f((u16)q1[j]), ksumf[c0 + 8 + j], part);
  float den = part + __shfl_xor(part, 1);
  if ((t & 1) == 0) rden[(size_t)row * 8 + (c0 >> 5)] = 1.f / (den + 1e-8f);
}

// ---------------- residual + LayerNorm ----------------
__global__ __launch_bounds__(256) void ln_k(const u16* __restrict__ outbf,
                                            const float* __restrict__ features,
                                            const float* __restrict__ gamma,
                                            const float* __restrict__ beta,
                                            float* __restrict__ y) {
  int wid = threadIdx.x >> 6, lane = threadIdx.x & 63;
  int row = blockIdx.x * 4 + wid;
  size_t base = (size_t)row * 256 + lane * 4;
  ushort4 ob = *(const ushort4*)(outbf + base);
  float4 ft = *(const float4*)(features + base);
  float y0 = bf2f(ob.x) + ft.x;
  float y1 = bf2f(ob.y) + ft.y;
  float y2 = bf2f(ob.z) + ft.z;
  float y3 = bf2f(ob.w) + ft.w;
  float s1 = y0 + y1 + y2 + y3;
  float s2 = y0 * y0 + y1 * y1 + y2 * y2 + y3 * y3;
#pragma unroll
  for (int off = 32; off; off >>= 1) {
    s1 += __shfl_xor(s1, off);
    s2 += __shfl_xor(s2, off);
  }
  float mu = s1 * (1.f / 256.f);
  float var = s2 * (1.f / 256.f) - mu * mu;
  float rstd = rsqrtf(fmaxf(var, 0.f) + 1e-5f);
  float4 g = *(const float4*)(gamma + lane * 4);
  float4 bt = *(const float4*)(beta + lane * 4);
  float4 o;
  o.x = (y0 - mu) * rstd * g.x + bt.x;
  o.y = (y1 - mu) * rstd * g.y + bt.y;
  o.z = (y2 - mu) * rstd * g.z + bt.z;
  o.w = (y3 - mu) * rstd * g.w + bt.w;
  *(float4*)(y + base) = o;
}

// ---------------- host ----------------
extern "C" void kernel_launch(void* const* d_in, const int* in_sizes, int n_in,
                              void* d_out, int out_size, void* d_ws, size_t ws_size,
                              hipStream_t stream) {
  const float* x     = (const float*)d_in[0];
  const float* feats = (const float*)d_in[1];
  const float* dlog  = (const float*)d_in[2];
  const float* w_dp  = (const float*)d_in[3];
  const float* b_dp  = (const float*)d_in[4];
  const float* wql   = (const float*)d_in[5];
  const float* bql   = (const float*)d_in[6];
  const float* wqh   = (const float*)d_in[7];
  const float* bqh   = (const float*)d_in[8];
  const float* wol   = (const float*)d_in[9];
  const float* bol   = (const float*)d_in[10];
  const float* woh   = (const float*)d_in[11];
  const float* boh   = (const float*)d_in[12];
  const float* adj   = (const float*)d_in[13];
  const float* geow  = (const float*)d_in[14];
  const float* gamma = (const float*)d_in[15];
  const float* beta  = (const float*)d_in[16];

  char* ws = (char*)d_ws;
  // total 136,290,304 B  (<= 136,843,264 proven available in round 1)
  constexpr size_t OFF_DW    = 0;
  constexpr size_t OFF_WLD   = 1024;
  constexpr size_t OFF_BLP   = 2048;
  constexpr size_t OFF_CVEC  = 4096;
  constexpr size_t OFF_DEL   = 8192;        // 256KB -> 270336
  constexpr size_t OFF_WQLT  = 270336;      // 256*256*2 -> 401408
  constexpr size_t OFF_WQHT  = 401408;      // 768*192*2 -> 696320
  constexpr size_t OFF_WOLT  = 696320;      // 128*256*2 -> 761856
  constexpr size_t OFF_KSP   = 761856;      // 8*256*32*4 -> 1024000
  constexpr size_t OFF_RDEN  = 1024000;     // 65536*8*4 -> 3121152
  constexpr size_t OFF_MM    = 3121152;     // 32*256*64*4 -> 5218304
  constexpr size_t OFF_B2T   = 5218304;     // 32*256*320*2 -> 10461184
  constexpr size_t OFF_LOW   = 10461184;    // 24MB -> 35627008 [dead after GQKV]
  constexpr size_t OFF_KVP   = OFF_LOW;               // 8MB [kvreduce..mmat]
  constexpr size_t OFF_VPT   = OFF_LOW + 8388608;     // 8MB [GVP..GGEO]
  constexpr size_t OFF_GEO2B = OFF_LOW + 16777216;    // 8MB [georeduce..GFIN]
  constexpr size_t OFF_QF    = 35627008;    // 32MB -> 69181440 [GQKV..GFIN]
  constexpr size_t OFF_KF    = 69181440;    // 32MB -> 102735872 [GQKV..kvreduce]
  constexpr size_t OFF_ADJB  = OFF_KF;      // 8MB [cvtadj..GGEO] (after kvreduce)
  constexpr size_t OFF_OUT   = OFF_KF;      // [GFIN..ln] (after GGEO)
  constexpr size_t OFF_V     = 102735872;   // 32MB -> 136290304 [GQKV..GVP]
  constexpr size_t OFF_GPART = OFF_V;       // 4x8MB [GGEO..georeduce] (after GVP)

  float* dw      = (float*)(ws + OFF_DW);
  float* wl_d    = (float*)(ws + OFF_WLD);
  float* bl_p    = (float*)(ws + OFF_BLP);
  float* cvec    = (float*)(ws + OFF_CVEC);
  float* delayed = (float*)(ws + OFF_DEL);
  float* kvpart  = (float*)(ws + OFF_KVP);
  float* kspart  = (float*)(ws + OFF_KSP);
  float* rden    = (float*)(ws + OFF_RDEN);
  float* Mm      = (float*)(ws + OFF_MM);
  u16* wqlT = (u16*)(ws + OFF_WQLT);
  u16* wqhT = (u16*)(ws + OFF_WQHT);
  u16* wolT = (u16*)(ws + OFF_WOLT);
  u16* B2t  = (u16*)(ws + OFF_B2T);
  u16* adjb = (u16*)(ws + OFF_ADJB);

  MArgs ma{};
  ma.delayed = delayed; ma.wl_d = wl_d; ma.bl_p = bl_p; ma.bqh = bqh;
  ma.rden = rden; ma.cvec = cvec;
  ma.adjb = adjb;
  ma.low = (u16*)(ws + OFF_LOW);
  ma.qf  = (u16*)(ws + OFF_QF);
  ma.kf  = (u16*)(ws + OFF_KF);
  ma.v   = (u16*)(ws + OFF_V);
  ma.geo2b = (u16*)(ws + OFF_GEO2B);
  ma.vpt   = (u16*)(ws + OFF_VPT);
  ma.outb  = (u16*)(ws + OFF_OUT);
  ma.geopart = (u16*)(ws + OFF_GPART);
  ma.geoA  = ma.geo2b;

  prep_k<<<1, 256, 0, stream>>>(dlog, w_dp, b_dp, wql, bql, dw, wl_d, bl_p);
  delayed_k<<<256, 256, 0, stream>>>(x, dw, delayed);
  tpose_k<<<256, 64, 0, stream>>>(wql, wqlT, 256, 192);
  tpose_k<<<768, 64, 0, stream>>>(wqh, wqhT, 192, 768);
  tpose_k<<<128, 64, 0, stream>>>(wol, wolT, 256, 64);

  MArgs m0 = ma; m0.Af32 = feats; m0.Bt = wqlT;
  mgemm_k<GLOW><<<dim3(2, 512), 256, 0, stream>>>(m0);       // low (bf16)

  MArgs m1 = ma; m1.A = ma.low; m1.Bt = wqhT;
  mgemm_k<GQKV><<<dim3(6, 512), 256, 0, stream>>>(m1);       // qf,kf,v (bf16)

  kvreduce_k<<<dim3(2, 8, 32), 256, 0, stream>>>(ma.kf, ma.v, kvpart, kspart);
  cvtadj_k<<<2048, 256, 0, stream>>>(adj, adjb);             // adj -> bf16 (kf region now dead)
  mmat_k<<<256, 64, 0, stream>>>(kvpart, wol, geow, Mm);
  bprep_k<<<dim3(4, 32), 256, 0, stream>>>(Mm, woh, bol, boh, geow, B2t, cvec);
  rden_k<<<4096, 256, 0, stream>>>(ma.qf, kspart, rden);

  MArgs m2 = ma; m2.A = ma.v; m2.Bt = wolT;
  mgemm_k<GVP><<<dim3(1, 512), 256, 0, stream>>>(m2);        // vpt = (v@Wol)^T bf16

  MArgs m3 = ma; m3.Bt = ma.vpt;
  mgemm_k<GGEO><<<dim3(16, 16, 4), 256, 0, stream>>>(m3);    // split-K=4 partials (bf16)
  georeduce_k<<<2048, 256, 0, stream>>>(ma.geopart, ma.geo2b);

  MArgs m4 = ma; m4.Bt = B2t;
  mgemm_k<GFIN><<<dim3(2, 512), 256, 0, stream>>>(m4);       // out = qs@MW + geo@gbWoh + cvec

  ln_k<<<16384, 256, 0, stream>>>(ma.outb, feats, gamma, beta, (float*)d_out);
  (void)in_sizes; (void)n_in; (void)out_size; (void)ws_size;
}